// Round 9
// baseline (318.562 us; speedup 1.0000x reference)
//
#include <hip/hip_runtime.h>

#define SEQ    2048
#define DMODEL 1024
#define NHEAD  16
#define DHEAD  64
#define NBATCH 2

typedef __bf16 bf16x8 __attribute__((ext_vector_type(8)));
typedef float f32x16 __attribute__((ext_vector_type(16)));
typedef float f32x8 __attribute__((ext_vector_type(8)));
typedef unsigned short ushort8v __attribute__((ext_vector_type(8)));
typedef unsigned int uint2v __attribute__((ext_vector_type(2)));
typedef int int4v __attribute__((ext_vector_type(4)));

static __device__ __forceinline__ unsigned short f2b(float f){
  unsigned int u = __builtin_bit_cast(unsigned int, f);
  u += 0x7fffu + ((u>>16)&1u);            // RNE to bf16
  return (unsigned short)(u>>16);
}
static __device__ __forceinline__ float b2f(unsigned short h){
  unsigned int u = ((unsigned int)h)<<16;
  return __builtin_bit_cast(float, u);
}
static __device__ __forceinline__ f32x16 mfma32(bf16x8 a, bf16x8 b, f32x16 c){
  return __builtin_amdgcn_mfma_f32_32x32x16_bf16(a,b,c,0,0,0);
}
static __device__ __forceinline__ ushort8v cvt8(const float* p){
  float4 f0 = *(const float4*)p;
  float4 f1 = *(const float4*)(p+4);
  ushort8v r;
  r[0]=f2b(f0.x); r[1]=f2b(f0.y); r[2]=f2b(f0.z); r[3]=f2b(f0.w);
  r[4]=f2b(f1.x); r[5]=f2b(f1.y); r[6]=f2b(f1.z); r[7]=f2b(f1.w);
  return r;
}

// ---------- pack X (q,k,v) fp32 -> bf16 MFMA-A-fragment order ----------
// Xp[g][s][lane][8] = X[g*32 + (lane&31)][16*s + 8*(lane>>5) + j]
__global__ __launch_bounds__(256) void cvtXpack(
    const float* __restrict__ q, const float* __restrict__ k, const float* __restrict__ v,
    unsigned short* __restrict__ Xq, unsigned short* __restrict__ Xk, unsigned short* __restrict__ Xv)
{
  const int z = blockIdx.z;
  const float* S = (z==0)? q : (z==1)? k : v;
  unsigned short* D = (z==0)? Xq : (z==1)? Xk : Xv;
  const int g = blockIdx.x;                       // 0..127
  const int wave = threadIdx.x>>6, lane = threadIdx.x&63;
  const int l31 = lane&31, hi = lane>>5;
  const float* src = S + (size_t)(g*32 + l31)*DMODEL + 8*hi + 256*wave;
  unsigned short* dst = D + (size_t)(g*64 + wave*16)*512 + lane*8;
  #pragma unroll
  for (int i=0;i<16;i++)
    *(ushort8v*)(dst + (size_t)i*512) = cvt8(src + 16*i);
}

// ---------- pack Wq,Wk,Wv,Wo fp32 -> bf16 MFMA-B-fragment order ----------
__global__ __launch_bounds__(256) void cvtWpack(
    const float* __restrict__ Wq, const float* __restrict__ Wk,
    const float* __restrict__ Wv, const float* __restrict__ Wo,
    unsigned short* __restrict__ Wp)
{
  const int z = blockIdx.z;
  const float* S = (z==0)? Wq : (z==1)? Wk : (z==2)? Wv : Wo;
  const int g = blockIdx.x;                       // 0..31
  const int wave = threadIdx.x>>6, lane = threadIdx.x&63;
  const int l31 = lane&31, hi = lane>>5;
  const float* src = S + (size_t)(g*32 + l31)*DMODEL + 8*hi + 256*wave;
  unsigned short* dst = Wp + (size_t)((z*32 + g)*64 + wave*16)*512 + lane*8;
  #pragma unroll
  for (int i=0;i<16;i++)
    *(ushort8v*)(dst + (size_t)i*512) = cvt8(src + 16*i);
}

// ---------- A packer (bf16): Am[q32][kt][w][lane][8] = bf16(A[k][q]) ----------
__global__ __launch_bounds__(256) void cvtA(const float* __restrict__ A,
                                            unsigned short* __restrict__ Am){
  const int tid  = threadIdx.x;
  const int lane = tid&63, l31 = lane&31, hi = lane>>5;
  const int q32  = blockIdx.x;                 // 0..63
  const int kt   = blockIdx.y*4 + (tid>>6);    // 0..31
  const int q    = q32*32 + l31;

  unsigned short out8[4][8];
  #pragma unroll
  for (int fi=0; fi<2; fi++){
    #pragma unroll
    for (int mm=0; mm<4; mm++){
      #pragma unroll
      for (int j=0; j<4; j++){
        const int k = kt*64 + 32*fi + 8*mm + 4*hi + j;
        out8[fi*2 + (mm>>1)][(mm&1)*4 + j] = f2b(A[(size_t)k*SEQ + q]);
      }
    }
  }
  unsigned short* dst = Am + ((size_t)(q32*32 + kt)*4)*512 + lane*8;
  #pragma unroll
  for (int w=0; w<4; w++)
    *(ushort8v*)(dst + (size_t)w*512) = *(const ushort8v*)out8[w];
}

// ---------- fused q/k/v projection: LDS-free fragment GEMM, sw-pipelined ----------
__global__ __launch_bounds__(256,3) void proj_qkv(
    const unsigned short* __restrict__ Xq, const unsigned short* __restrict__ Xk, const unsigned short* __restrict__ Xv,
    const unsigned short* __restrict__ Wp,
    const float* __restrict__ bq, const float* __restrict__ bk, const float* __restrict__ bv,
    unsigned short* __restrict__ qh, unsigned short* __restrict__ Kp, unsigned short* __restrict__ Vp)
{
  const int z = blockIdx.z;
  const unsigned short* X = (z==0)? Xq : (z==1)? Xk : Xv;
  const unsigned short* W = Wp + (size_t)z*1048576;
  const float* bias = (z==0)? bq : (z==1)? bk : bv;
  const float alpha = (z==0)? 0.125f : 1.0f;   // fold 1/sqrt(DK) into qh

  const int orig = blockIdx.y*8 + blockIdx.x;
  const int virt = (orig&7)*32 + (orig>>3);
  const int bx = virt&7, by = virt>>3;
  const int mb = by*128, nb = bx*128;

  const int tid = threadIdx.x;
  const int lane = tid&63, wave = tid>>6;
  const int wr = wave>>1, wc = wave&1, l31 = lane&31, hi = lane>>5;
  f32x16 acc[2][2] = {};

  const unsigned short* a0p = X + (size_t)((mb>>5) + 2*wr)*32768 + lane*8;
  const unsigned short* a1p = a0p + 32768;
  const unsigned short* b0p = W + (size_t)((nb>>5) + 2*wc)*32768 + lane*8;
  const unsigned short* b1p = b0p + 32768;

  bf16x8 Ca[4], Cb[4];
  #define LDP(D,S) { \
    D[0] = *(const bf16x8*)(a0p + (size_t)(S)*512); \
    D[1] = *(const bf16x8*)(a1p + (size_t)(S)*512); \
    D[2] = *(const bf16x8*)(b0p + (size_t)(S)*512); \
    D[3] = *(const bf16x8*)(b1p + (size_t)(S)*512); }
  LDP(Ca,0)
  #pragma unroll 1
  for (int s=0; s<64; s+=2){
    LDP(Cb, s+1)
    acc[0][0] = mfma32(Ca[0],Ca[2],acc[0][0]);
    acc[0][1] = mfma32(Ca[0],Ca[3],acc[0][1]);
    acc[1][0] = mfma32(Ca[1],Ca[2],acc[1][0]);
    acc[1][1] = mfma32(Ca[1],Ca[3],acc[1][1]);
    LDP(Ca, (s+2)&63)
    acc[0][0] = mfma32(Cb[0],Cb[2],acc[0][0]);
    acc[0][1] = mfma32(Cb[0],Cb[3],acc[0][1]);
    acc[1][0] = mfma32(Cb[1],Cb[2],acc[1][0]);
    acc[1][1] = mfma32(Cb[1],Cb[3],acc[1][1]);
  }
  #undef LDP

  #pragma unroll
  for (int fj=0; fj<2; fj++){
    const int e = nb + 64*wc + 32*fj + l31;
    const float bv_ = bias[e];
    const int hh = e>>6, dk = e&63;
    #pragma unroll
    for (int fi=0; fi<2; fi++){
      #pragma unroll
      for (int r=0;r<16;r++){
        const int i = mb + 64*wr + 32*fi + (r&3) + 8*(r>>2) + 4*hi;
        const int bb = i>>11, ss = i&(SEQ-1);
        const int bhh = bb*NHEAD + hh;
        const unsigned short val = f2b((acc[fi][fj][r] + bv_)*alpha);
        if (z==0){
          qh[((size_t)bhh*SEQ + ss)*DHEAD + dk] = val;
        } else if (z==1){
          const size_t addr = (((size_t)(bhh*64 + (ss>>5))*4 + (dk>>4))*64
                               + ((dk>>3)&1)*32 + (ss&31))*8 + (dk&7);
          Kp[addr] = val;
        } else {
          const size_t addr = ((((size_t)(bhh*32 + (ss>>6))*4 + ((ss>>4)&3))*2
                               + (dk>>5))*64 + ((ss>>3)&1)*32 + (dk&31))*8 + (ss&7);
          Vp[addr] = val;
        }
      }
    }
  }
}

// ---------- fused masked attention: x = (Qh Kh^T ∘ A^T) Vh ----------
// 256 threads = 4 waves = 2 q32 x 2 khalf; 64 q-rows/block; grid 1024 (4/CU).
// One-iteration-deep register prefetch of K and A (ping-pong, 2x unrolled).
__global__ __launch_bounds__(256,4) void attn(
    const unsigned short* __restrict__ qh, const unsigned short* __restrict__ Kp,
    const unsigned short* __restrict__ Vp, const unsigned short* __restrict__ Am,
    unsigned short* __restrict__ xp)
{
  // 1024 blocks: xcd = orig&7 owns bh in [xcd*4, xcd*4+4)
  const int orig = blockIdx.y*32 + blockIdx.x;
  const int xcd = orig&7, within = orig>>3;   // within 0..127
  const int bh   = xcd*4 + (within>>5);       // 0..31
  const int qblk = within&31;                 // 0..31 (64 q-rows each)

  const int tid  = threadIdx.x;
  const int lane = tid&63, wave = tid>>6;
  const int qsub = wave&1, khalf = wave>>1;
  const int l31 = lane&31, hi = lane>>5;

  const int q32  = qblk*2 + qsub;
  const int qrow = q32*32 + l31;
  const unsigned short* qp = qh + ((size_t)bh*SEQ + qrow)*DHEAD;
  bf16x8 Qf[4];
  #pragma unroll
  for (int t=0;t<4;t++) Qf[t] = *(const bf16x8*)(qp + 16*t + 8*hi);

  f32x16 xacc[2] = {};

  const unsigned short* kpb = Kp + ((size_t)bh*64)*2048 + lane*8;   // [k32][s][lane][8]
  const unsigned short* vpb = Vp + ((size_t)bh*32)*4096 + lane*8;   // [k64][s2][dhalf][lane][8]
  const unsigned short* apb = Am + ((size_t)q32*32)*2048 + lane*8;  // [kt][w][lane][8] bf16

  bf16x8 Ka[8], Kb[8];
  ushort8v Aa[4], Ab[4];

  #define LOADK(DST, KT) { \
    const unsigned short* _kp = kpb + (size_t)((KT)*2)*2048; \
    _Pragma("unroll") \
    for (int s=0;s<8;s++) DST[s] = *(const bf16x8*)(_kp + (size_t)s*512); }
  #define LOADA(DST, KT) { \
    const unsigned short* _ap = apb + (size_t)(KT)*2048; \
    _Pragma("unroll") \
    for (int w=0;w<4;w++) DST[w] = *(const ushort8v*)(_ap + (size_t)w*512); }

  LOADK(Ka, khalf*16);
  LOADA(Aa, khalf*16);

  #define BODY(T, KR, AR, KN, AN, TN) { \
    const int _kt = khalf*16 + (T); \
    const unsigned short* _vp = vpb + (size_t)_kt*4096; \
    bf16x8 Vr[8]; \
    _Pragma("unroll") \
    for (int s=0;s<8;s++) Vr[s] = *(const bf16x8*)(_vp + (size_t)s*512); \
    LOADK(KN, khalf*16 + (TN)); \
    LOADA(AN, khalf*16 + (TN)); \
    unsigned int wv[2][4], xv[2][4]; \
    _Pragma("unroll") \
    for (int fi=0; fi<2; fi++){ \
      f32x16 sacc = {}; \
      _Pragma("unroll") \
      for (int s=0;s<4;s++) \
        sacc = mfma32(KR[fi*4+s], Qf[s], sacc); \
      ushort8v a80 = AR[fi*2+0], a81 = AR[fi*2+1]; \
      _Pragma("unroll") \
      for (int mm=0; mm<4; mm++){ \
        const int b0 = (mm&1)*4, rb2 = 4*mm; \
        float p0 = sacc[rb2+0]*((mm>>1)? b2f(a81[b0+0]) : b2f(a80[b0+0])); \
        float p1 = sacc[rb2+1]*((mm>>1)? b2f(a81[b0+1]) : b2f(a80[b0+1])); \
        float p2 = sacc[rb2+2]*((mm>>1)? b2f(a81[b0+2]) : b2f(a80[b0+2])); \
        float p3 = sacc[rb2+3]*((mm>>1)? b2f(a81[b0+3]) : b2f(a80[b0+3])); \
        asm("v_cvt_pk_bf16_f32 %0, %1, %2" : "=v"(wv[fi][mm]) : "v"(p0), "v"(p1)); \
        asm("v_cvt_pk_bf16_f32 %0, %1, %2" : "=v"(xv[fi][mm]) : "v"(p2), "v"(p3)); \
      } \
    } \
    __builtin_amdgcn_s_setprio(1); \
    _Pragma("unroll") \
    for (int s2=0; s2<4; s2++){ \
      const int fi = s2>>1, sl = s2&1; \
      uint2v rw = __builtin_amdgcn_permlane32_swap(wv[fi][2*sl], wv[fi][2*sl+1], false, false); \
      uint2v rx = __builtin_amdgcn_permlane32_swap(xv[fi][2*sl], xv[fi][2*sl+1], false, false); \
      int4v av; av.x = (int)rw[0]; av.y = (int)rx[0]; av.z = (int)rw[1]; av.w = (int)rx[1]; \
      bf16x8 pa = __builtin_bit_cast(bf16x8, av); \
      xacc[0] = mfma32(pa, Vr[s2*2+0], xacc[0]); \
      xacc[1] = mfma32(pa, Vr[s2*2+1], xacc[1]); \
    } \
    __builtin_amdgcn_s_setprio(0); }

  #pragma unroll 1
  for (int tt=0; tt<8; tt++){
    const int t0 = 2*tt, t1 = 2*tt+1;
    BODY(t0, Ka, Aa, Kb, Ab, t1);
    BODY(t1, Kb, Ab, Ka, Aa, (t1+1)&15);
  }
  #undef BODY
  #undef LOADK
  #undef LOADA

  // cross-wave split-K reduction (single barrier)
  __shared__ float Red[2][64][33];
  if (khalf==1){
    #pragma unroll
    for (int j=0;j<2;j++)
      #pragma unroll
      for (int r=0;r<16;r++)
        Red[qsub][lane][16*j+r] = xacc[j][r];
  }
  __syncthreads();
  if (khalf==0){
    #pragma unroll
    for (int j=0;j<2;j++)
      #pragma unroll
      for (int r=0;r<16;r++)
        xacc[j][r] += Red[qsub][lane][16*j+r];
    const int b = bh>>4, h = bh&15;
    #pragma unroll
    for (int fj=0; fj<2; fj++){
      const int scol = h*4 + fj*2 + (l31>>4);
      const int lpart = ((l31>>3)&1)*32;
      const int epart = l31&7;
      #pragma unroll
      for (int r=0;r<16;r++){
        const int qq = q32*32 + (r&3) + 8*(r>>2) + 4*hi;
        const int row = b*SEQ + qq;
        const size_t addr = ((size_t)(row>>5)*64 + scol)*512 + (lpart + (row&31))*8 + epart;
        xp[addr] = f2b(xacc[fj][r]);
      }
    }
  }
}

// ---------- output projection: LDS-free fragment GEMM, sw-pipelined, fp32 out ----------
__global__ __launch_bounds__(256,4) void oproj(
    const unsigned short* __restrict__ Xp, const unsigned short* __restrict__ Wop,
    const float* __restrict__ bo, float* __restrict__ out)
{
  const int orig = blockIdx.y*16 + blockIdx.x;
  const int virt = (orig&7)*64 + (orig>>3);
  const int bx = virt&15, by = virt>>4;
  const int mb = by*128, nb = bx*64;

  const int tid = threadIdx.x;
  const int lane = tid&63, wave = tid>>6;
  const int l31 = lane&31, hi = lane>>5;
  f32x16 acc[2] = {};

  const unsigned short* ap  = Xp  + (size_t)((mb>>5) + wave)*32768 + lane*8;
  const unsigned short* b0p = Wop + (size_t)(nb>>5)*32768 + lane*8;
  const unsigned short* b1p = b0p + 32768;

  bf16x8 Ca[3], Cb[3];
  #define LDO(D,S) { \
    D[0] = *(const bf16x8*)(ap  + (size_t)(S)*512); \
    D[1] = *(const bf16x8*)(b0p + (size_t)(S)*512); \
    D[2] = *(const bf16x8*)(b1p + (size_t)(S)*512); }
  LDO(Ca,0)
  #pragma unroll 1
  for (int s=0; s<64; s+=2){
    LDO(Cb, s+1)
    acc[0] = mfma32(Ca[0],Ca[1],acc[0]);
    acc[1] = mfma32(Ca[0],Ca[2],acc[1]);
    LDO(Ca, (s+2)&63)
    acc[0] = mfma32(Cb[0],Cb[1],acc[0]);
    acc[1] = mfma32(Cb[0],Cb[2],acc[1]);
  }
  #undef LDO

  #pragma unroll
  for (int fj=0; fj<2; fj++){
    const int e = nb + 32*fj + l31;
    const float bv_ = bo[e];
    #pragma unroll
    for (int r=0;r<16;r++){
      const int i = mb + 32*wave + (r&3) + 8*(r>>2) + 4*hi;
      out[(size_t)i*DMODEL + e] = acc[fj][r] + bv_;
    }
  }
}

extern "C" void kernel_launch(void* const* d_in, const int* in_sizes, int n_in,
                              void* d_out, int out_size, void* d_ws, size_t ws_size,
                              hipStream_t stream)
{
  const float* q  = (const float*)d_in[0];
  const float* k  = (const float*)d_in[1];
  const float* v  = (const float*)d_in[2];
  const float* A  = (const float*)d_in[3];
  const float* Wq = (const float*)d_in[4];
  const float* bq = (const float*)d_in[5];
  const float* Wk = (const float*)d_in[6];
  const float* bk = (const float*)d_in[7];
  const float* Wv = (const float*)d_in[8];
  const float* bv = (const float*)d_in[9];
  const float* Wo = (const float*)d_in[10];
  const float* bo = (const float*)d_in[11];
  float* out = (float*)d_out;

  // ws (bf16 elems): qh, Kp, Vp, xb, Wp -> 40MB. d_out as scratch:
  //   phase1: Xqp [0,8MB), Xkp [8,16MB)   (consumed by proj)
  //   phase2: Am bf16 [0,8MB)             (written by cvtA after proj, read by attn)
  //   phase3: final fp32 out              (oproj)
  unsigned short* ws = (unsigned short*)d_ws;
  const size_t NE = (size_t)NBATCH*SEQ*DMODEL;   // 4M elements
  unsigned short* qh  = ws;
  unsigned short* Kp  = qh + NE;
  unsigned short* Vp  = Kp + NE;
  unsigned short* xb  = Vp + NE;                 // Xvp before attn, packed-x after
  unsigned short* Wp  = xb + NE;                 // 4 packed weight matrices
  unsigned short* Xqp = (unsigned short*)d_out;
  unsigned short* Xkp = Xqp + NE;
  unsigned short* Am  = (unsigned short*)d_out;  // bf16 2048x2048 = 8MB
  unsigned short* Xvp = xb;

  cvtXpack<<<dim3(128, 1, 3), 256, 0, stream>>>(q, k, v, Xqp, Xkp, Xvp);
  cvtWpack<<<dim3(32, 1, 4), 256, 0, stream>>>(Wq, Wk, Wv, Wo, Wp);
  proj_qkv<<<dim3(8, 32, 3), 256, 0, stream>>>(
      Xqp, Xkp, Xvp, Wp, bq, bk, bv, qh, Kp, Vp);
  cvtA<<<dim3(64, 8), 256, 0, stream>>>(A, Am);
  attn<<<dim3(32, 32), 256, 0, stream>>>(qh, Kp, Vp, Am, xb);
  oproj<<<dim3(16, 32), 256, 0, stream>>>(xb, Wp + (size_t)3*1048576, bo, out);
}

// Round 10
// 142.523 us; speedup vs baseline: 2.2352x; 2.2352x over previous
//
#include <hip/hip_runtime.h>

#define SEQ    2048
#define DMODEL 1024
#define NHEAD  16
#define DHEAD  64
#define NBATCH 2

typedef __bf16 bf16x8 __attribute__((ext_vector_type(8)));
typedef float f32x16 __attribute__((ext_vector_type(16)));
typedef float f32x8 __attribute__((ext_vector_type(8)));
typedef unsigned short ushort8v __attribute__((ext_vector_type(8)));
typedef unsigned int uint2v __attribute__((ext_vector_type(2)));
typedef int int4v __attribute__((ext_vector_type(4)));

static __device__ __forceinline__ unsigned short f2b(float f){
  unsigned int u = __builtin_bit_cast(unsigned int, f);
  u += 0x7fffu + ((u>>16)&1u);            // RNE to bf16
  return (unsigned short)(u>>16);
}
static __device__ __forceinline__ float b2f(unsigned short h){
  unsigned int u = ((unsigned int)h)<<16;
  return __builtin_bit_cast(float, u);
}
static __device__ __forceinline__ f32x16 mfma32(bf16x8 a, bf16x8 b, f32x16 c){
  return __builtin_amdgcn_mfma_f32_32x32x16_bf16(a,b,c,0,0,0);
}
static __device__ __forceinline__ ushort8v cvt8(const float* p){
  float4 f0 = *(const float4*)p;
  float4 f1 = *(const float4*)(p+4);
  ushort8v r;
  r[0]=f2b(f0.x); r[1]=f2b(f0.y); r[2]=f2b(f0.z); r[3]=f2b(f0.w);
  r[4]=f2b(f1.x); r[5]=f2b(f1.y); r[6]=f2b(f1.z); r[7]=f2b(f1.w);
  return r;
}

// ---------- pack X (q,k,v) fp32 -> bf16 MFMA-A-fragment order ----------
// Xp[g][s][lane][8] = X[g*32 + (lane&31)][16*s + 8*(lane>>5) + j]
__global__ __launch_bounds__(256) void cvtXpack(
    const float* __restrict__ q, const float* __restrict__ k, const float* __restrict__ v,
    unsigned short* __restrict__ Xq, unsigned short* __restrict__ Xk, unsigned short* __restrict__ Xv)
{
  const int z = blockIdx.z;
  const float* S = (z==0)? q : (z==1)? k : v;
  unsigned short* D = (z==0)? Xq : (z==1)? Xk : Xv;
  const int g = blockIdx.x;                       // 0..127
  const int wave = threadIdx.x>>6, lane = threadIdx.x&63;
  const int l31 = lane&31, hi = lane>>5;
  const float* src = S + (size_t)(g*32 + l31)*DMODEL + 8*hi + 256*wave;
  unsigned short* dst = D + (size_t)(g*64 + wave*16)*512 + lane*8;
  #pragma unroll
  for (int i=0;i<16;i++)
    *(ushort8v*)(dst + (size_t)i*512) = cvt8(src + 16*i);
}

// ---------- pack Wq,Wk,Wv,Wo fp32 -> bf16 MFMA-B-fragment order ----------
__global__ __launch_bounds__(256) void cvtWpack(
    const float* __restrict__ Wq, const float* __restrict__ Wk,
    const float* __restrict__ Wv, const float* __restrict__ Wo,
    unsigned short* __restrict__ Wp)
{
  const int z = blockIdx.z;
  const float* S = (z==0)? Wq : (z==1)? Wk : (z==2)? Wv : Wo;
  const int g = blockIdx.x;                       // 0..31
  const int wave = threadIdx.x>>6, lane = threadIdx.x&63;
  const int l31 = lane&31, hi = lane>>5;
  const float* src = S + (size_t)(g*32 + l31)*DMODEL + 8*hi + 256*wave;
  unsigned short* dst = Wp + (size_t)((z*32 + g)*64 + wave*16)*512 + lane*8;
  #pragma unroll
  for (int i=0;i<16;i++)
    *(ushort8v*)(dst + (size_t)i*512) = cvt8(src + 16*i);
}

// ---------- A packer (bf16): Am[q32][kt][w][lane][8] = bf16(A[k][q]) ----------
__global__ __launch_bounds__(256) void cvtA(const float* __restrict__ A,
                                            unsigned short* __restrict__ Am){
  const int tid  = threadIdx.x;
  const int lane = tid&63, l31 = lane&31, hi = lane>>5;
  const int q32  = blockIdx.x;                 // 0..63
  const int kt   = blockIdx.y*4 + (tid>>6);    // 0..31
  const int q    = q32*32 + l31;

  unsigned short out8[4][8];
  #pragma unroll
  for (int fi=0; fi<2; fi++){
    #pragma unroll
    for (int mm=0; mm<4; mm++){
      #pragma unroll
      for (int j=0; j<4; j++){
        const int k = kt*64 + 32*fi + 8*mm + 4*hi + j;
        out8[fi*2 + (mm>>1)][(mm&1)*4 + j] = f2b(A[(size_t)k*SEQ + q]);
      }
    }
  }
  unsigned short* dst = Am + ((size_t)(q32*32 + kt)*4)*512 + lane*8;
  #pragma unroll
  for (int w=0; w<4; w++)
    *(ushort8v*)(dst + (size_t)w*512) = *(const ushort8v*)out8[w];
}

// ---------- fused q/k/v projection: LDS-free, barrier-free fragment GEMM ----------
__global__ __launch_bounds__(256,3) void proj_qkv(
    const unsigned short* __restrict__ Xq, const unsigned short* __restrict__ Xk, const unsigned short* __restrict__ Xv,
    const unsigned short* __restrict__ Wp,
    const float* __restrict__ bq, const float* __restrict__ bk, const float* __restrict__ bv,
    unsigned short* __restrict__ qh, unsigned short* __restrict__ Kp, unsigned short* __restrict__ Vp)
{
  const int z = blockIdx.z;
  const unsigned short* X = (z==0)? Xq : (z==1)? Xk : Xv;
  const unsigned short* W = Wp + (size_t)z*1048576;
  const float* bias = (z==0)? bq : (z==1)? bk : bv;
  const float alpha = (z==0)? 0.125f : 1.0f;   // fold 1/sqrt(DK) into qh

  const int orig = blockIdx.y*8 + blockIdx.x;
  const int virt = (orig&7)*32 + (orig>>3);
  const int bx = virt&7, by = virt>>3;
  const int mb = by*128, nb = bx*128;

  const int tid = threadIdx.x;
  const int lane = tid&63, wave = tid>>6;
  const int wr = wave>>1, wc = wave&1, l31 = lane&31, hi = lane>>5;
  f32x16 acc[2][2] = {};

  const unsigned short* a0p = X + (size_t)((mb>>5) + 2*wr)*32768 + lane*8;
  const unsigned short* a1p = a0p + 32768;
  const unsigned short* b0p = W + (size_t)((nb>>5) + 2*wc)*32768 + lane*8;
  const unsigned short* b1p = b0p + 32768;

  #pragma unroll 4
  for (int s=0;s<64;s++){
    bf16x8 a0 = *(const bf16x8*)(a0p + (size_t)s*512);
    bf16x8 a1 = *(const bf16x8*)(a1p + (size_t)s*512);
    bf16x8 b0 = *(const bf16x8*)(b0p + (size_t)s*512);
    bf16x8 b1 = *(const bf16x8*)(b1p + (size_t)s*512);
    acc[0][0] = mfma32(a0,b0,acc[0][0]);
    acc[0][1] = mfma32(a0,b1,acc[0][1]);
    acc[1][0] = mfma32(a1,b0,acc[1][0]);
    acc[1][1] = mfma32(a1,b1,acc[1][1]);
  }

  #pragma unroll
  for (int fj=0; fj<2; fj++){
    const int e = nb + 64*wc + 32*fj + l31;
    const float bv_ = bias[e];
    const int hh = e>>6, dk = e&63;
    #pragma unroll
    for (int fi=0; fi<2; fi++){
      #pragma unroll
      for (int r=0;r<16;r++){
        const int i = mb + 64*wr + 32*fi + (r&3) + 8*(r>>2) + 4*hi;
        const int bb = i>>11, ss = i&(SEQ-1);
        const int bhh = bb*NHEAD + hh;
        const unsigned short val = f2b((acc[fi][fj][r] + bv_)*alpha);
        if (z==0){
          qh[((size_t)bhh*SEQ + ss)*DHEAD + dk] = val;
        } else if (z==1){
          const size_t addr = (((size_t)(bhh*64 + (ss>>5))*4 + (dk>>4))*64
                               + ((dk>>3)&1)*32 + (ss&31))*8 + (dk&7);
          Kp[addr] = val;
        } else {
          const size_t addr = ((((size_t)(bhh*32 + (ss>>6))*4 + ((ss>>4)&3))*2
                               + (dk>>5))*64 + ((ss>>3)&1)*32 + (dk&31))*8 + (ss&7);
          Vp[addr] = val;
        }
      }
    }
  }
}

// ---------- fused masked attention: x = (Qh Kh^T ∘ A^T) Vh ----------
// 512 threads = 8 waves = 4 q32 x 2 khalf; 128 q-rows/block.
// One-iteration-deep register prefetch of K and A (ping-pong, 2x unrolled);
// V loaded at iteration top so QK^T+mask covers its L2 latency.
__global__ __launch_bounds__(512,2) void attn(
    const unsigned short* __restrict__ qh, const unsigned short* __restrict__ Kp,
    const unsigned short* __restrict__ Vp, const unsigned short* __restrict__ Am,
    unsigned short* __restrict__ xp)
{
  // 512 blocks: xcd = orig&7 owns bh in [xcd*4, xcd*4+4)
  const int orig = blockIdx.y*16 + blockIdx.x;
  const int xcd = orig&7, within = orig>>3;
  const int bh   = xcd*4 + (within>>4);   // 0..31
  const int qblk = within&15;             // 0..15 (128 q-rows each)

  const int tid  = threadIdx.x;
  const int lane = tid&63, wave = tid>>6;
  const int qsub = wave&3, khalf = wave>>2;
  const int l31 = lane&31, hi = lane>>5;

  const int q32  = qblk*4 + qsub;
  const int qrow = q32*32 + l31;
  const unsigned short* qp = qh + ((size_t)bh*SEQ + qrow)*DHEAD;
  bf16x8 Qf[4];
  #pragma unroll
  for (int t=0;t<4;t++) Qf[t] = *(const bf16x8*)(qp + 16*t + 8*hi);

  f32x16 xacc[2] = {};

  const unsigned short* kpb = Kp + ((size_t)bh*64)*2048 + lane*8;   // [k32][s][lane][8]
  const unsigned short* vpb = Vp + ((size_t)bh*32)*4096 + lane*8;   // [k64][s2][dhalf][lane][8]
  const unsigned short* apb = Am + ((size_t)q32*32)*2048 + lane*8;  // [kt][w][lane][8] bf16

  bf16x8 Ka[8], Kb[8];
  ushort8v Aa[4], Ab[4];

  #define LOADK(DST, KT) { \
    const unsigned short* _kp = kpb + (size_t)((KT)*2)*2048; \
    _Pragma("unroll") \
    for (int s=0;s<8;s++) DST[s] = *(const bf16x8*)(_kp + (size_t)s*512); }
  #define LOADA(DST, KT) { \
    const unsigned short* _ap = apb + (size_t)(KT)*2048; \
    _Pragma("unroll") \
    for (int w=0;w<4;w++) DST[w] = *(const ushort8v*)(_ap + (size_t)w*512); }

  LOADK(Ka, khalf*16);
  LOADA(Aa, khalf*16);

  #define BODY(T, KR, AR, KN, AN, TN) { \
    const int _kt = khalf*16 + (T); \
    const unsigned short* _vp = vpb + (size_t)_kt*4096; \
    bf16x8 Vr[8]; \
    _Pragma("unroll") \
    for (int s=0;s<8;s++) Vr[s] = *(const bf16x8*)(_vp + (size_t)s*512); \
    LOADK(KN, khalf*16 + (TN)); \
    LOADA(AN, khalf*16 + (TN)); \
    unsigned int wv[2][4], xv[2][4]; \
    _Pragma("unroll") \
    for (int fi=0; fi<2; fi++){ \
      f32x16 sacc = {}; \
      _Pragma("unroll") \
      for (int s=0;s<4;s++) \
        sacc = mfma32(KR[fi*4+s], Qf[s], sacc); \
      ushort8v a80 = AR[fi*2+0], a81 = AR[fi*2+1]; \
      _Pragma("unroll") \
      for (int mm=0; mm<4; mm++){ \
        const int b0 = (mm&1)*4, rb2 = 4*mm; \
        float p0 = sacc[rb2+0]*((mm>>1)? b2f(a81[b0+0]) : b2f(a80[b0+0])); \
        float p1 = sacc[rb2+1]*((mm>>1)? b2f(a81[b0+1]) : b2f(a80[b0+1])); \
        float p2 = sacc[rb2+2]*((mm>>1)? b2f(a81[b0+2]) : b2f(a80[b0+2])); \
        float p3 = sacc[rb2+3]*((mm>>1)? b2f(a81[b0+3]) : b2f(a80[b0+3])); \
        asm("v_cvt_pk_bf16_f32 %0, %1, %2" : "=v"(wv[fi][mm]) : "v"(p0), "v"(p1)); \
        asm("v_cvt_pk_bf16_f32 %0, %1, %2" : "=v"(xv[fi][mm]) : "v"(p2), "v"(p3)); \
      } \
    } \
    __builtin_amdgcn_s_setprio(1); \
    _Pragma("unroll") \
    for (int s2=0; s2<4; s2++){ \
      const int fi = s2>>1, sl = s2&1; \
      uint2v rw = __builtin_amdgcn_permlane32_swap(wv[fi][2*sl], wv[fi][2*sl+1], false, false); \
      uint2v rx = __builtin_amdgcn_permlane32_swap(xv[fi][2*sl], xv[fi][2*sl+1], false, false); \
      int4v av; av.x = (int)rw[0]; av.y = (int)rx[0]; av.z = (int)rw[1]; av.w = (int)rx[1]; \
      bf16x8 pa = __builtin_bit_cast(bf16x8, av); \
      xacc[0] = mfma32(pa, Vr[s2*2+0], xacc[0]); \
      xacc[1] = mfma32(pa, Vr[s2*2+1], xacc[1]); \
    } \
    __builtin_amdgcn_s_setprio(0); }

  #pragma unroll 1
  for (int tt=0; tt<8; tt++){
    const int t0 = 2*tt, t1 = 2*tt+1;
    BODY(t0, Ka, Aa, Kb, Ab, t1);
    BODY(t1, Kb, Ab, Ka, Aa, (t1+1)&15);
  }
  #undef BODY
  #undef LOADK
  #undef LOADA

  // cross-wave split-K reduction (single barrier)
  __shared__ float Red[4][64][33];
  if (khalf==1){
    #pragma unroll
    for (int j=0;j<2;j++)
      #pragma unroll
      for (int r=0;r<16;r++)
        Red[qsub][lane][16*j+r] = xacc[j][r];
  }
  __syncthreads();
  if (khalf==0){
    #pragma unroll
    for (int j=0;j<2;j++)
      #pragma unroll
      for (int r=0;r<16;r++)
        xacc[j][r] += Red[qsub][lane][16*j+r];
    const int b = bh>>4, h = bh&15;
    #pragma unroll
    for (int fj=0; fj<2; fj++){
      const int scol = h*4 + fj*2 + (l31>>4);
      const int lpart = ((l31>>3)&1)*32;
      const int epart = l31&7;
      #pragma unroll
      for (int r=0;r<16;r++){
        const int qq = q32*32 + (r&3) + 8*(r>>2) + 4*hi;
        const int row = b*SEQ + qq;
        const size_t addr = ((size_t)(row>>5)*64 + scol)*512 + (lpart + (row&31))*8 + epart;
        xp[addr] = f2b(xacc[fj][r]);
      }
    }
  }
}

// ---------- output projection: LDS-free fragment GEMM, fp32 out ----------
__global__ __launch_bounds__(256,4) void oproj(
    const unsigned short* __restrict__ Xp, const unsigned short* __restrict__ Wop,
    const float* __restrict__ bo, float* __restrict__ out)
{
  const int orig = blockIdx.y*16 + blockIdx.x;
  const int virt = (orig&7)*64 + (orig>>3);
  const int bx = virt&15, by = virt>>4;
  const int mb = by*128, nb = bx*64;

  const int tid = threadIdx.x;
  const int lane = tid&63, wave = tid>>6;
  const int l31 = lane&31, hi = lane>>5;
  f32x16 acc[2] = {};

  const unsigned short* ap  = Xp  + (size_t)((mb>>5) + wave)*32768 + lane*8;
  const unsigned short* b0p = Wop + (size_t)(nb>>5)*32768 + lane*8;
  const unsigned short* b1p = b0p + 32768;

  #pragma unroll 4
  for (int s=0;s<64;s++){
    bf16x8 a  = *(const bf16x8*)(ap  + (size_t)s*512);
    bf16x8 b0 = *(const bf16x8*)(b0p + (size_t)s*512);
    bf16x8 b1 = *(const bf16x8*)(b1p + (size_t)s*512);
    acc[0] = mfma32(a,b0,acc[0]);
    acc[1] = mfma32(a,b1,acc[1]);
  }

  #pragma unroll
  for (int fj=0; fj<2; fj++){
    const int e = nb + 32*fj + l31;
    const float bv_ = bo[e];
    #pragma unroll
    for (int r=0;r<16;r++){
      const int i = mb + 32*wave + (r&3) + 8*(r>>2) + 4*hi;
      out[(size_t)i*DMODEL + e] = acc[fj][r] + bv_;
    }
  }
}

extern "C" void kernel_launch(void* const* d_in, const int* in_sizes, int n_in,
                              void* d_out, int out_size, void* d_ws, size_t ws_size,
                              hipStream_t stream)
{
  const float* q  = (const float*)d_in[0];
  const float* k  = (const float*)d_in[1];
  const float* v  = (const float*)d_in[2];
  const float* A  = (const float*)d_in[3];
  const float* Wq = (const float*)d_in[4];
  const float* bq = (const float*)d_in[5];
  const float* Wk = (const float*)d_in[6];
  const float* bk = (const float*)d_in[7];
  const float* Wv = (const float*)d_in[8];
  const float* bv = (const float*)d_in[9];
  const float* Wo = (const float*)d_in[10];
  const float* bo = (const float*)d_in[11];
  float* out = (float*)d_out;

  // ws (bf16 elems): qh, Kp, Vp, xb, Wp -> 40MB. d_out as scratch:
  //   phase1: Xqp [0,8MB), Xkp [8,16MB)   (consumed by proj)
  //   phase2: Am bf16 [0,8MB)             (written by cvtA after proj, read by attn)
  //   phase3: final fp32 out              (oproj)
  unsigned short* ws = (unsigned short*)d_ws;
  const size_t NE = (size_t)NBATCH*SEQ*DMODEL;   // 4M elements
  unsigned short* qh  = ws;
  unsigned short* Kp  = qh + NE;
  unsigned short* Vp  = Kp + NE;
  unsigned short* xb  = Vp + NE;                 // Xvp before attn, packed-x after
  unsigned short* Wp  = xb + NE;                 // 4 packed weight matrices
  unsigned short* Xqp = (unsigned short*)d_out;
  unsigned short* Xkp = Xqp + NE;
  unsigned short* Am  = (unsigned short*)d_out;  // bf16 2048x2048 = 8MB
  unsigned short* Xvp = xb;

  cvtXpack<<<dim3(128, 1, 3), 256, 0, stream>>>(q, k, v, Xqp, Xkp, Xvp);
  cvtWpack<<<dim3(32, 1, 4), 256, 0, stream>>>(Wq, Wk, Wv, Wo, Wp);
  proj_qkv<<<dim3(8, 32, 3), 256, 0, stream>>>(
      Xqp, Xkp, Xvp, Wp, bq, bk, bv, qh, Kp, Vp);
  cvtA<<<dim3(64, 8), 256, 0, stream>>>(A, Am);
  attn<<<dim3(16, 32), 512, 0, stream>>>(qh, Kp, Vp, Am, xb);
  oproj<<<dim3(16, 32), 256, 0, stream>>>(xb, Wp + (size_t)3*1048576, bo, out);
}

// Round 11
// 133.706 us; speedup vs baseline: 2.3826x; 1.0659x over previous
//
#include <hip/hip_runtime.h>

#define SEQ    2048
#define DMODEL 1024
#define NHEAD  16
#define DHEAD  64
#define NBATCH 2

typedef __bf16 bf16x8 __attribute__((ext_vector_type(8)));
typedef float f32x16 __attribute__((ext_vector_type(16)));
typedef float f32x8 __attribute__((ext_vector_type(8)));
typedef unsigned short ushort8v __attribute__((ext_vector_type(8)));
typedef unsigned int uint2v __attribute__((ext_vector_type(2)));
typedef int int4v __attribute__((ext_vector_type(4)));

static __device__ __forceinline__ unsigned short f2b(float f){
  unsigned int u = __builtin_bit_cast(unsigned int, f);
  u += 0x7fffu + ((u>>16)&1u);            // RNE to bf16
  return (unsigned short)(u>>16);
}
static __device__ __forceinline__ float b2f(unsigned short h){
  unsigned int u = ((unsigned int)h)<<16;
  return __builtin_bit_cast(float, u);
}
static __device__ __forceinline__ f32x16 mfma32(bf16x8 a, bf16x8 b, f32x16 c){
  return __builtin_amdgcn_mfma_f32_32x32x16_bf16(a,b,c,0,0,0);
}
static __device__ __forceinline__ ushort8v cvt8(const float* p){
  float4 f0 = *(const float4*)p;
  float4 f1 = *(const float4*)(p+4);
  ushort8v r;
  r[0]=f2b(f0.x); r[1]=f2b(f0.y); r[2]=f2b(f0.z); r[3]=f2b(f0.w);
  r[4]=f2b(f1.x); r[5]=f2b(f1.y); r[6]=f2b(f1.z); r[7]=f2b(f1.w);
  return r;
}
#define GLOAD16(g,l) __builtin_amdgcn_global_load_lds( \
    (const __attribute__((address_space(1))) void*)(g), \
    (__attribute__((address_space(3))) void*)(l), 16, 0, 0)

// ---------- pack X (q,k,v) fp32 -> bf16 MFMA-A-fragment order ----------
// Xp[g][s][lane][8] = X[g*32 + (lane&31)][16*s + 8*(lane>>5) + j]
__global__ __launch_bounds__(256) void cvtXpack(
    const float* __restrict__ q, const float* __restrict__ k, const float* __restrict__ v,
    unsigned short* __restrict__ Xq, unsigned short* __restrict__ Xk, unsigned short* __restrict__ Xv)
{
  const int z = blockIdx.z;
  const float* S = (z==0)? q : (z==1)? k : v;
  unsigned short* D = (z==0)? Xq : (z==1)? Xk : Xv;
  const int g = blockIdx.x;                       // 0..127
  const int wave = threadIdx.x>>6, lane = threadIdx.x&63;
  const int l31 = lane&31, hi = lane>>5;
  const float* src = S + (size_t)(g*32 + l31)*DMODEL + 8*hi + 256*wave;
  unsigned short* dst = D + (size_t)(g*64 + wave*16)*512 + lane*8;
  #pragma unroll
  for (int i=0;i<16;i++)
    *(ushort8v*)(dst + (size_t)i*512) = cvt8(src + 16*i);
}

// ---------- pack Wq,Wk,Wv,Wo fp32 -> bf16 MFMA-B-fragment order ----------
__global__ __launch_bounds__(256) void cvtWpack(
    const float* __restrict__ Wq, const float* __restrict__ Wk,
    const float* __restrict__ Wv, const float* __restrict__ Wo,
    unsigned short* __restrict__ Wp)
{
  const int z = blockIdx.z;
  const float* S = (z==0)? Wq : (z==1)? Wk : (z==2)? Wv : Wo;
  const int g = blockIdx.x;                       // 0..31
  const int wave = threadIdx.x>>6, lane = threadIdx.x&63;
  const int l31 = lane&31, hi = lane>>5;
  const float* src = S + (size_t)(g*32 + l31)*DMODEL + 8*hi + 256*wave;
  unsigned short* dst = Wp + (size_t)((z*32 + g)*64 + wave*16)*512 + lane*8;
  #pragma unroll
  for (int i=0;i<16;i++)
    *(ushort8v*)(dst + (size_t)i*512) = cvt8(src + 16*i);
}

// ---------- A packer (bf16): Am[q32][kt][w][lane][8] = bf16(A[k][q]) ----------
__global__ __launch_bounds__(256) void cvtA(const float* __restrict__ A,
                                            unsigned short* __restrict__ Am){
  const int tid  = threadIdx.x;
  const int lane = tid&63, l31 = lane&31, hi = lane>>5;
  const int q32  = blockIdx.x;                 // 0..63
  const int kt   = blockIdx.y*4 + (tid>>6);    // 0..31
  const int q    = q32*32 + l31;

  unsigned short out8[4][8];
  #pragma unroll
  for (int fi=0; fi<2; fi++){
    #pragma unroll
    for (int mm=0; mm<4; mm++){
      #pragma unroll
      for (int j=0; j<4; j++){
        const int k = kt*64 + 32*fi + 8*mm + 4*hi + j;
        out8[fi*2 + (mm>>1)][(mm&1)*4 + j] = f2b(A[(size_t)k*SEQ + q]);
      }
    }
  }
  unsigned short* dst = Am + ((size_t)(q32*32 + kt)*4)*512 + lane*8;
  #pragma unroll
  for (int w=0; w<4; w++)
    *(ushort8v*)(dst + (size_t)w*512) = *(const ushort8v*)out8[w];
}

// ---------- fused q/k/v projection: LDS-free, barrier-free fragment GEMM ----------
__global__ __launch_bounds__(256,3) void proj_qkv(
    const unsigned short* __restrict__ Xq, const unsigned short* __restrict__ Xk, const unsigned short* __restrict__ Xv,
    const unsigned short* __restrict__ Wp,
    const float* __restrict__ bq, const float* __restrict__ bk, const float* __restrict__ bv,
    unsigned short* __restrict__ qh, unsigned short* __restrict__ Kp, unsigned short* __restrict__ Vp)
{
  const int z = blockIdx.z;
  const unsigned short* X = (z==0)? Xq : (z==1)? Xk : Xv;
  const unsigned short* W = Wp + (size_t)z*1048576;
  const float* bias = (z==0)? bq : (z==1)? bk : bv;
  const float alpha = (z==0)? 0.125f : 1.0f;   // fold 1/sqrt(DK) into qh

  const int orig = blockIdx.y*8 + blockIdx.x;
  const int virt = (orig&7)*32 + (orig>>3);
  const int bx = virt&7, by = virt>>3;
  const int mb = by*128, nb = bx*128;

  const int tid = threadIdx.x;
  const int lane = tid&63, wave = tid>>6;
  const int wr = wave>>1, wc = wave&1, l31 = lane&31, hi = lane>>5;
  f32x16 acc[2][2] = {};

  const unsigned short* a0p = X + (size_t)((mb>>5) + 2*wr)*32768 + lane*8;
  const unsigned short* a1p = a0p + 32768;
  const unsigned short* b0p = W + (size_t)((nb>>5) + 2*wc)*32768 + lane*8;
  const unsigned short* b1p = b0p + 32768;

  #pragma unroll 4
  for (int s=0;s<64;s++){
    bf16x8 a0 = *(const bf16x8*)(a0p + (size_t)s*512);
    bf16x8 a1 = *(const bf16x8*)(a1p + (size_t)s*512);
    bf16x8 b0 = *(const bf16x8*)(b0p + (size_t)s*512);
    bf16x8 b1 = *(const bf16x8*)(b1p + (size_t)s*512);
    acc[0][0] = mfma32(a0,b0,acc[0][0]);
    acc[0][1] = mfma32(a0,b1,acc[0][1]);
    acc[1][0] = mfma32(a1,b0,acc[1][0]);
    acc[1][1] = mfma32(a1,b1,acc[1][1]);
  }

  #pragma unroll
  for (int fj=0; fj<2; fj++){
    const int e = nb + 64*wc + 32*fj + l31;
    const float bv_ = bias[e];
    const int hh = e>>6, dk = e&63;
    #pragma unroll
    for (int fi=0; fi<2; fi++){
      #pragma unroll
      for (int r=0;r<16;r++){
        const int i = mb + 64*wr + 32*fi + (r&3) + 8*(r>>2) + 4*hi;
        const int bb = i>>11, ss = i&(SEQ-1);
        const int bhh = bb*NHEAD + hh;
        const unsigned short val = f2b((acc[fi][fj][r] + bv_)*alpha);
        if (z==0){
          qh[((size_t)bhh*SEQ + ss)*DHEAD + dk] = val;
        } else if (z==1){
          const size_t addr = (((size_t)(bhh*64 + (ss>>5))*4 + (dk>>4))*64
                               + ((dk>>3)&1)*32 + (ss&31))*8 + (dk&7);
          Kp[addr] = val;
        } else {
          const size_t addr = ((((size_t)(bhh*32 + (ss>>6))*4 + ((ss>>4)&3))*2
                               + (dk>>5))*64 + ((ss>>3)&1)*32 + (dk&31))*8 + (ss&7);
          Vp[addr] = val;
        }
      }
    }
  }
}

// ---------- fused masked attention: x = (Qh Kh^T ∘ A^T) Vh ----------
// 256 threads = 4 waves = 4 q32 (128 q-rows/block), full K sweep per wave.
// K/V double-buffered in LDS via global_load_lds (fragment layout is already
// linear lane*16B -> native gload_lds pattern, conflict-free ds_read_b128).
// A register ping-pong prefetch. One vmcnt(0)+barrier per k-tile (m97 pattern).
__global__ __launch_bounds__(256,2) void attn(
    const unsigned short* __restrict__ qh, const unsigned short* __restrict__ Kp,
    const unsigned short* __restrict__ Vp, const unsigned short* __restrict__ Am,
    unsigned short* __restrict__ xp)
{
  // 512 blocks: xcd = orig&7 owns bh in [xcd*4, xcd*4+4) -> K/V slice 2MB, L2-resident
  const int orig = blockIdx.y*16 + blockIdx.x;
  const int xcd = orig&7, within = orig>>3;   // within 0..63
  const int bh   = xcd*4 + (within>>4);       // 0..31
  const int qblk = within&15;                 // 0..15 (128 q-rows each)

  const int tid  = threadIdx.x;
  const int lane = tid&63, wave = tid>>6;     // wave = q-subtile 0..3
  const int l31 = lane&31, hi = lane>>5;

  const int q32  = qblk*4 + wave;
  const int qrow = q32*32 + l31;
  const unsigned short* qp = qh + ((size_t)bh*SEQ + qrow)*DHEAD;
  bf16x8 Qf[4];
  #pragma unroll
  for (int t=0;t<4;t++) Qf[t] = *(const bf16x8*)(qp + 16*t + 8*hi);

  f32x16 xacc[2] = {};

  const unsigned short* kpb = Kp + (size_t)bh*131072 + lane*8;   // [k32][s][lane][8]
  const unsigned short* vpb = Vp + (size_t)bh*131072 + lane*8;   // [k64][frag][lane][8]
  const unsigned short* apb = Am + (size_t)q32*65536 + lane*8;   // [kt][w][lane][8]

  __shared__ unsigned short Klds[2][4096];
  __shared__ unsigned short Vlds[2][4096];

  ushort8v Aa[4], Ab[4];

  // wave w stages K frags {2w,2w+1} and V frags {2w,2w+1} of the k-tile
  #define STAGE(BUF, KT) { \
    const unsigned short* _k = kpb + (size_t)(KT)*4096; \
    const unsigned short* _v = vpb + (size_t)(KT)*4096; \
    GLOAD16(_k + (size_t)(2*wave  )*512, &Klds[BUF][(2*wave  )*512]); \
    GLOAD16(_k + (size_t)(2*wave+1)*512, &Klds[BUF][(2*wave+1)*512]); \
    GLOAD16(_v + (size_t)(2*wave  )*512, &Vlds[BUF][(2*wave  )*512]); \
    GLOAD16(_v + (size_t)(2*wave+1)*512, &Vlds[BUF][(2*wave+1)*512]); }

  #define LOADA(DST, KT) { \
    const unsigned short* _ap = apb + (size_t)(KT)*2048; \
    _Pragma("unroll") \
    for (int w=0;w<4;w++) DST[w] = *(const ushort8v*)(_ap + (size_t)w*512); }

  STAGE(0, 0);
  LOADA(Aa, 0);
  __syncthreads();

  // BODY: stage k-tile KT+1 into BUF^1, prefetch A[KT+1] into AN,
  //       compute k-tile KT from BUF with mask AR; barrier at end.
  #define BODY(KT, BUF, AR, AN) { \
    STAGE((BUF)^1, ((KT)+1)&31); \
    LOADA(AN, ((KT)+1)&31); \
    unsigned int wv[2][4], xv[2][4]; \
    _Pragma("unroll") \
    for (int fi=0; fi<2; fi++){ \
      f32x16 sacc = {}; \
      _Pragma("unroll") \
      for (int s=0;s<4;s++){ \
        bf16x8 kf = *(const bf16x8*)&Klds[BUF][(fi*4+s)*512 + lane*8]; \
        sacc = mfma32(kf, Qf[s], sacc); \
      } \
      ushort8v a80 = AR[fi*2+0], a81 = AR[fi*2+1]; \
      _Pragma("unroll") \
      for (int mm=0; mm<4; mm++){ \
        const int b0 = (mm&1)*4, rb2 = 4*mm; \
        float p0 = sacc[rb2+0]*((mm>>1)? b2f(a81[b0+0]) : b2f(a80[b0+0])); \
        float p1 = sacc[rb2+1]*((mm>>1)? b2f(a81[b0+1]) : b2f(a80[b0+1])); \
        float p2 = sacc[rb2+2]*((mm>>1)? b2f(a81[b0+2]) : b2f(a80[b0+2])); \
        float p3 = sacc[rb2+3]*((mm>>1)? b2f(a81[b0+3]) : b2f(a80[b0+3])); \
        asm("v_cvt_pk_bf16_f32 %0, %1, %2" : "=v"(wv[fi][mm]) : "v"(p0), "v"(p1)); \
        asm("v_cvt_pk_bf16_f32 %0, %1, %2" : "=v"(xv[fi][mm]) : "v"(p2), "v"(p3)); \
      } \
    } \
    __builtin_amdgcn_s_setprio(1); \
    _Pragma("unroll") \
    for (int s2=0; s2<4; s2++){ \
      const int fi = s2>>1, sl = s2&1; \
      uint2v rw = __builtin_amdgcn_permlane32_swap(wv[fi][2*sl], wv[fi][2*sl+1], false, false); \
      uint2v rx = __builtin_amdgcn_permlane32_swap(xv[fi][2*sl], xv[fi][2*sl+1], false, false); \
      int4v av; av.x = (int)rw[0]; av.y = (int)rx[0]; av.z = (int)rw[1]; av.w = (int)rx[1]; \
      bf16x8 pa = __builtin_bit_cast(bf16x8, av); \
      bf16x8 v0 = *(const bf16x8*)&Vlds[BUF][(s2*2+0)*512 + lane*8]; \
      bf16x8 v1 = *(const bf16x8*)&Vlds[BUF][(s2*2+1)*512 + lane*8]; \
      xacc[0] = mfma32(pa, v0, xacc[0]); \
      xacc[1] = mfma32(pa, v1, xacc[1]); \
    } \
    __builtin_amdgcn_s_setprio(0); \
    __syncthreads(); }

  #pragma unroll 1
  for (int tt=0; tt<16; tt++){
    BODY(2*tt,   0, Aa, Ab);
    BODY(2*tt+1, 1, Ab, Aa);
  }
  #undef BODY
  #undef STAGE
  #undef LOADA

  // epilogue: each wave owns its q32 sub-tile; write packed x fragments
  const int b = bh>>4, h = bh&15;
  #pragma unroll
  for (int fj=0; fj<2; fj++){
    const int scol = h*4 + fj*2 + (l31>>4);
    const int lpart = ((l31>>3)&1)*32;
    const int epart = l31&7;
    #pragma unroll
    for (int r=0;r<16;r++){
      const int qq = q32*32 + (r&3) + 8*(r>>2) + 4*hi;
      const int row = b*SEQ + qq;
      const size_t addr = ((size_t)(row>>5)*64 + scol)*512 + (lpart + (row&31))*8 + epart;
      xp[addr] = f2b(xacc[fj][r]);
    }
  }
}

// ---------- output projection: LDS-free fragment GEMM, fp32 out ----------
__global__ __launch_bounds__(256,4) void oproj(
    const unsigned short* __restrict__ Xp, const unsigned short* __restrict__ Wop,
    const float* __restrict__ bo, float* __restrict__ out)
{
  const int orig = blockIdx.y*16 + blockIdx.x;
  const int virt = (orig&7)*64 + (orig>>3);
  const int bx = virt&15, by = virt>>4;
  const int mb = by*128, nb = bx*64;

  const int tid = threadIdx.x;
  const int lane = tid&63, wave = tid>>6;
  const int l31 = lane&31, hi = lane>>5;
  f32x16 acc[2] = {};

  const unsigned short* ap  = Xp  + (size_t)((mb>>5) + wave)*32768 + lane*8;
  const unsigned short* b0p = Wop + (size_t)(nb>>5)*32768 + lane*8;
  const unsigned short* b1p = b0p + 32768;

  #pragma unroll 4
  for (int s=0;s<64;s++){
    bf16x8 a  = *(const bf16x8*)(ap  + (size_t)s*512);
    bf16x8 b0 = *(const bf16x8*)(b0p + (size_t)s*512);
    bf16x8 b1 = *(const bf16x8*)(b1p + (size_t)s*512);
    acc[0] = mfma32(a,b0,acc[0]);
    acc[1] = mfma32(a,b1,acc[1]);
  }

  #pragma unroll
  for (int fj=0; fj<2; fj++){
    const int e = nb + 32*fj + l31;
    const float bv_ = bo[e];
    #pragma unroll
    for (int r=0;r<16;r++){
      const int i = mb + 32*wave + (r&3) + 8*(r>>2) + 4*hi;
      out[(size_t)i*DMODEL + e] = acc[fj][r] + bv_;
    }
  }
}

extern "C" void kernel_launch(void* const* d_in, const int* in_sizes, int n_in,
                              void* d_out, int out_size, void* d_ws, size_t ws_size,
                              hipStream_t stream)
{
  const float* q  = (const float*)d_in[0];
  const float* k  = (const float*)d_in[1];
  const float* v  = (const float*)d_in[2];
  const float* A  = (const float*)d_in[3];
  const float* Wq = (const float*)d_in[4];
  const float* bq = (const float*)d_in[5];
  const float* Wk = (const float*)d_in[6];
  const float* bk = (const float*)d_in[7];
  const float* Wv = (const float*)d_in[8];
  const float* bv = (const float*)d_in[9];
  const float* Wo = (const float*)d_in[10];
  const float* bo = (const float*)d_in[11];
  float* out = (float*)d_out;

  // ws (bf16 elems): qh, Kp, Vp, xb, Wp -> 40MB. d_out as scratch:
  //   phase1: Xqp [0,8MB), Xkp [8,16MB)   (consumed by proj)
  //   phase2: Am bf16 [0,8MB)             (written by cvtA after proj, read by attn)
  //   phase3: final fp32 out              (oproj)
  unsigned short* ws = (unsigned short*)d_ws;
  const size_t NE = (size_t)NBATCH*SEQ*DMODEL;   // 4M elements
  unsigned short* qh  = ws;
  unsigned short* Kp  = qh + NE;
  unsigned short* Vp  = Kp + NE;
  unsigned short* xb  = Vp + NE;                 // Xvp before attn, packed-x after
  unsigned short* Wp  = xb + NE;                 // 4 packed weight matrices
  unsigned short* Xqp = (unsigned short*)d_out;
  unsigned short* Xkp = Xqp + NE;
  unsigned short* Am  = (unsigned short*)d_out;  // bf16 2048x2048 = 8MB
  unsigned short* Xvp = xb;

  cvtXpack<<<dim3(128, 1, 3), 256, 0, stream>>>(q, k, v, Xqp, Xkp, Xvp);
  cvtWpack<<<dim3(32, 1, 4), 256, 0, stream>>>(Wq, Wk, Wv, Wo, Wp);
  proj_qkv<<<dim3(8, 32, 3), 256, 0, stream>>>(
      Xqp, Xkp, Xvp, Wp, bq, bk, bv, qh, Kp, Vp);
  cvtA<<<dim3(64, 8), 256, 0, stream>>>(A, Am);
  attn<<<dim3(16, 32), 256, 0, stream>>>(qh, Kp, Vp, Am, xb);
  oproj<<<dim3(16, 32), 256, 0, stream>>>(xb, Wp + (size_t)3*1048576, bo, out);
}

// Round 12
// 133.497 us; speedup vs baseline: 2.3863x; 1.0016x over previous
//
#include <hip/hip_runtime.h>

#define SEQ    2048
#define DMODEL 1024
#define NHEAD  16
#define DHEAD  64
#define NBATCH 2

typedef __bf16 bf16x8 __attribute__((ext_vector_type(8)));
typedef float f32x16 __attribute__((ext_vector_type(16)));
typedef float f32x8 __attribute__((ext_vector_type(8)));
typedef unsigned short ushort8v __attribute__((ext_vector_type(8)));
typedef unsigned int uint2v __attribute__((ext_vector_type(2)));
typedef int int4v __attribute__((ext_vector_type(4)));

static __device__ __forceinline__ unsigned short f2b(float f){
  unsigned int u = __builtin_bit_cast(unsigned int, f);
  u += 0x7fffu + ((u>>16)&1u);            // RNE to bf16
  return (unsigned short)(u>>16);
}
static __device__ __forceinline__ float b2f(unsigned short h){
  unsigned int u = ((unsigned int)h)<<16;
  return __builtin_bit_cast(float, u);
}
static __device__ __forceinline__ f32x16 mfma32(bf16x8 a, bf16x8 b, f32x16 c){
  return __builtin_amdgcn_mfma_f32_32x32x16_bf16(a,b,c,0,0,0);
}
static __device__ __forceinline__ ushort8v cvt8(const float* p){
  float4 f0 = *(const float4*)p;
  float4 f1 = *(const float4*)(p+4);
  ushort8v r;
  r[0]=f2b(f0.x); r[1]=f2b(f0.y); r[2]=f2b(f0.z); r[3]=f2b(f0.w);
  r[4]=f2b(f1.x); r[5]=f2b(f1.y); r[6]=f2b(f1.z); r[7]=f2b(f1.w);
  return r;
}
#define GLOAD16(g,l) __builtin_amdgcn_global_load_lds( \
    (const __attribute__((address_space(1))) void*)(g), \
    (__attribute__((address_space(3))) void*)(l), 16, 0, 0)

// ---------- pack X (q,k,v) fp32 -> bf16 MFMA-A-fragment order ----------
// Xp[g][s][lane][8] = X[g*32 + (lane&31)][16*s + 8*(lane>>5) + j]
__global__ __launch_bounds__(256) void cvtXpack(
    const float* __restrict__ q, const float* __restrict__ k, const float* __restrict__ v,
    unsigned short* __restrict__ Xq, unsigned short* __restrict__ Xk, unsigned short* __restrict__ Xv)
{
  const int z = blockIdx.z;
  const float* S = (z==0)? q : (z==1)? k : v;
  unsigned short* D = (z==0)? Xq : (z==1)? Xk : Xv;
  const int g = blockIdx.x;                       // 0..127
  const int wave = threadIdx.x>>6, lane = threadIdx.x&63;
  const int l31 = lane&31, hi = lane>>5;
  const float* src = S + (size_t)(g*32 + l31)*DMODEL + 8*hi + 256*wave;
  unsigned short* dst = D + (size_t)(g*64 + wave*16)*512 + lane*8;
  #pragma unroll
  for (int i=0;i<16;i++)
    *(ushort8v*)(dst + (size_t)i*512) = cvt8(src + 16*i);
}

// ---------- pack Wq,Wk,Wv,Wo fp32 -> bf16 MFMA-B-fragment order ----------
__global__ __launch_bounds__(256) void cvtWpack(
    const float* __restrict__ Wq, const float* __restrict__ Wk,
    const float* __restrict__ Wv, const float* __restrict__ Wo,
    unsigned short* __restrict__ Wp)
{
  const int z = blockIdx.z;
  const float* S = (z==0)? Wq : (z==1)? Wk : (z==2)? Wv : Wo;
  const int g = blockIdx.x;                       // 0..31
  const int wave = threadIdx.x>>6, lane = threadIdx.x&63;
  const int l31 = lane&31, hi = lane>>5;
  const float* src = S + (size_t)(g*32 + l31)*DMODEL + 8*hi + 256*wave;
  unsigned short* dst = Wp + (size_t)((z*32 + g)*64 + wave*16)*512 + lane*8;
  #pragma unroll
  for (int i=0;i<16;i++)
    *(ushort8v*)(dst + (size_t)i*512) = cvt8(src + 16*i);
}

// ---------- A packer (bf16): Am[q32][kt][w][lane][8] = bf16(A[k][q]) ----------
__global__ __launch_bounds__(256) void cvtA(const float* __restrict__ A,
                                            unsigned short* __restrict__ Am){
  const int tid  = threadIdx.x;
  const int lane = tid&63, l31 = lane&31, hi = lane>>5;
  const int q32  = blockIdx.x;                 // 0..63
  const int kt   = blockIdx.y*4 + (tid>>6);    // 0..31
  const int q    = q32*32 + l31;

  unsigned short out8[4][8];
  #pragma unroll
  for (int fi=0; fi<2; fi++){
    #pragma unroll
    for (int mm=0; mm<4; mm++){
      #pragma unroll
      for (int j=0; j<4; j++){
        const int k = kt*64 + 32*fi + 8*mm + 4*hi + j;
        out8[fi*2 + (mm>>1)][(mm&1)*4 + j] = f2b(A[(size_t)k*SEQ + q]);
      }
    }
  }
  unsigned short* dst = Am + ((size_t)(q32*32 + kt)*4)*512 + lane*8;
  #pragma unroll
  for (int w=0; w<4; w++)
    *(ushort8v*)(dst + (size_t)w*512) = *(const ushort8v*)out8[w];
}

// ---------- fused q/k/v projection: LDS-free, barrier-free fragment GEMM ----------
__global__ __launch_bounds__(256,3) void proj_qkv(
    const unsigned short* __restrict__ Xq, const unsigned short* __restrict__ Xk, const unsigned short* __restrict__ Xv,
    const unsigned short* __restrict__ Wp,
    const float* __restrict__ bq, const float* __restrict__ bk, const float* __restrict__ bv,
    unsigned short* __restrict__ qh, unsigned short* __restrict__ Kp, unsigned short* __restrict__ Vp)
{
  const int z = blockIdx.z;
  const unsigned short* X = (z==0)? Xq : (z==1)? Xk : Xv;
  const unsigned short* W = Wp + (size_t)z*1048576;
  const float* bias = (z==0)? bq : (z==1)? bk : bv;
  const float alpha = (z==0)? 0.125f : 1.0f;   // fold 1/sqrt(DK) into qh

  const int orig = blockIdx.y*8 + blockIdx.x;
  const int virt = (orig&7)*32 + (orig>>3);
  const int bx = virt&7, by = virt>>3;
  const int mb = by*128, nb = bx*128;

  const int tid = threadIdx.x;
  const int lane = tid&63, wave = tid>>6;
  const int wr = wave>>1, wc = wave&1, l31 = lane&31, hi = lane>>5;
  f32x16 acc[2][2] = {};

  const unsigned short* a0p = X + (size_t)((mb>>5) + 2*wr)*32768 + lane*8;
  const unsigned short* a1p = a0p + 32768;
  const unsigned short* b0p = W + (size_t)((nb>>5) + 2*wc)*32768 + lane*8;
  const unsigned short* b1p = b0p + 32768;

  #pragma unroll 4
  for (int s=0;s<64;s++){
    bf16x8 a0 = *(const bf16x8*)(a0p + (size_t)s*512);
    bf16x8 a1 = *(const bf16x8*)(a1p + (size_t)s*512);
    bf16x8 b0 = *(const bf16x8*)(b0p + (size_t)s*512);
    bf16x8 b1 = *(const bf16x8*)(b1p + (size_t)s*512);
    acc[0][0] = mfma32(a0,b0,acc[0][0]);
    acc[0][1] = mfma32(a0,b1,acc[0][1]);
    acc[1][0] = mfma32(a1,b0,acc[1][0]);
    acc[1][1] = mfma32(a1,b1,acc[1][1]);
  }

  #pragma unroll
  for (int fj=0; fj<2; fj++){
    const int e = nb + 64*wc + 32*fj + l31;
    const float bv_ = bias[e];
    const int hh = e>>6, dk = e&63;
    #pragma unroll
    for (int fi=0; fi<2; fi++){
      #pragma unroll
      for (int r=0;r<16;r++){
        const int i = mb + 64*wr + 32*fi + (r&3) + 8*(r>>2) + 4*hi;
        const int bb = i>>11, ss = i&(SEQ-1);
        const int bhh = bb*NHEAD + hh;
        const unsigned short val = f2b((acc[fi][fj][r] + bv_)*alpha);
        if (z==0){
          qh[((size_t)bhh*SEQ + ss)*DHEAD + dk] = val;
        } else if (z==1){
          const size_t addr = (((size_t)(bhh*64 + (ss>>5))*4 + (dk>>4))*64
                               + ((dk>>3)&1)*32 + (ss&31))*8 + (dk&7);
          Kp[addr] = val;
        } else {
          const size_t addr = ((((size_t)(bhh*32 + (ss>>6))*4 + ((ss>>4)&3))*2
                               + (dk>>5))*64 + ((ss>>3)&1)*32 + (dk&31))*8 + (ss&7);
          Vp[addr] = val;
        }
      }
    }
  }
}

// ---------- fused masked attention: x = (Qh Kh^T ∘ A^T) Vh ----------
// 512 threads = 8 waves = 4 qsub x 2 khalf; 128 q-rows/block; 512 blocks = 2/CU.
// All 8 waves share one K/V LDS stream (double-buffered, global_load_lds);
// each wave computes its fi=khalf half of every k-tile (4+4 MFMA).
// Partial sums reduced through the staging LDS (dead after the loop).
__global__ __launch_bounds__(512,4) void attn(
    const unsigned short* __restrict__ qh, const unsigned short* __restrict__ Kp,
    const unsigned short* __restrict__ Vp, const unsigned short* __restrict__ Am,
    unsigned short* __restrict__ xp)
{
  // 512 blocks: xcd = orig&7 owns bh in [xcd*4, xcd*4+4) -> K/V slice L2-resident
  const int orig = blockIdx.y*16 + blockIdx.x;
  const int xcd = orig&7, within = orig>>3;   // within 0..63
  const int bh   = xcd*4 + (within>>4);       // 0..31
  const int qblk = within&15;                 // 0..15 (128 q-rows each)

  const int tid  = threadIdx.x;
  const int lane = tid&63, wave = tid>>6;     // wave 0..7
  const int qsub = wave&3, khalf = wave>>2;
  const int l31 = lane&31, hi = lane>>5;

  const int q32  = qblk*4 + qsub;
  const int qrow = q32*32 + l31;
  const unsigned short* qp = qh + ((size_t)bh*SEQ + qrow)*DHEAD;
  bf16x8 Qf[4];
  #pragma unroll
  for (int t=0;t<4;t++) Qf[t] = *(const bf16x8*)(qp + 16*t + 8*hi);

  f32x16 xacc[2] = {};

  const unsigned short* kpb = Kp + (size_t)bh*131072 + lane*8;   // [kt][frag][lane][8]
  const unsigned short* vpb = Vp + (size_t)bh*131072 + lane*8;
  const unsigned short* apb = Am + (size_t)q32*65536 + lane*8;   // [kt][w][lane][8]

  // staging: [buf][16 frags (K 0..7 | V 8..15)][512 shorts] = 32 KB;
  // reused post-loop as float Red[4][64][33] = 33792 B
  __shared__ float SMEMf[8448];
  unsigned short* smem = (unsigned short*)SMEMf;

  // wave w stages combined frags {2w, 2w+1}
  const unsigned short* gsb = ((wave<4)? kpb : vpb);
  const int fo = (wave&3)*2;                       // fragment pair within K or V
  const int dof = ((wave<4)? 0 : 4096) + fo*512;   // LDS dest offset (shorts)

  ushort8v Aa[2], Ab[2];

  #define STAGE(BUF, KT) { \
    const unsigned short* _g = gsb + (size_t)(KT)*4096 + (size_t)fo*512; \
    GLOAD16(_g,       smem + (BUF)*8192 + dof); \
    GLOAD16(_g + 512, smem + (BUF)*8192 + dof + 512); }

  #define LOADA(DST, KT) { \
    const unsigned short* _ap = apb + (size_t)(KT)*2048 + (size_t)(khalf*2)*512; \
    DST[0] = *(const ushort8v*)(_ap); \
    DST[1] = *(const ushort8v*)(_ap + 512); }

  STAGE(0, 0);
  LOADA(Aa, 0);
  __syncthreads();

  // BODY: stage tile KT+1 into BUF^1, prefetch A[KT+1]; compute fi=khalf of tile KT.
  #define BODY(KT, BUF, AR, AN) { \
    STAGE((BUF)^1, ((KT)+1)&31); \
    LOADA(AN, ((KT)+1)&31); \
    unsigned int wv[4], xv[4]; \
    { \
      f32x16 sacc = {}; \
      _Pragma("unroll") \
      for (int s=0;s<4;s++){ \
        bf16x8 kf = *(const bf16x8*)(smem + (BUF)*8192 + (khalf*4+s)*512 + lane*8); \
        sacc = mfma32(kf, Qf[s], sacc); \
      } \
      ushort8v a80 = AR[0], a81 = AR[1]; \
      _Pragma("unroll") \
      for (int mm=0; mm<4; mm++){ \
        const int b0 = (mm&1)*4, rb2 = 4*mm; \
        float p0 = sacc[rb2+0]*((mm>>1)? b2f(a81[b0+0]) : b2f(a80[b0+0])); \
        float p1 = sacc[rb2+1]*((mm>>1)? b2f(a81[b0+1]) : b2f(a80[b0+1])); \
        float p2 = sacc[rb2+2]*((mm>>1)? b2f(a81[b0+2]) : b2f(a80[b0+2])); \
        float p3 = sacc[rb2+3]*((mm>>1)? b2f(a81[b0+3]) : b2f(a80[b0+3])); \
        asm("v_cvt_pk_bf16_f32 %0, %1, %2" : "=v"(wv[mm]) : "v"(p0), "v"(p1)); \
        asm("v_cvt_pk_bf16_f32 %0, %1, %2" : "=v"(xv[mm]) : "v"(p2), "v"(p3)); \
      } \
    } \
    __builtin_amdgcn_s_setprio(1); \
    _Pragma("unroll") \
    for (int sl=0; sl<2; sl++){ \
      const int s2 = 2*khalf + sl; \
      uint2v rw = __builtin_amdgcn_permlane32_swap(wv[2*sl], wv[2*sl+1], false, false); \
      uint2v rx = __builtin_amdgcn_permlane32_swap(xv[2*sl], xv[2*sl+1], false, false); \
      int4v av; av.x = (int)rw[0]; av.y = (int)rx[0]; av.z = (int)rw[1]; av.w = (int)rx[1]; \
      bf16x8 pa = __builtin_bit_cast(bf16x8, av); \
      bf16x8 v0 = *(const bf16x8*)(smem + (BUF)*8192 + 4096 + (s2*2+0)*512 + lane*8); \
      bf16x8 v1 = *(const bf16x8*)(smem + (BUF)*8192 + 4096 + (s2*2+1)*512 + lane*8); \
      xacc[0] = mfma32(pa, v0, xacc[0]); \
      xacc[1] = mfma32(pa, v1, xacc[1]); \
    } \
    __builtin_amdgcn_s_setprio(0); \
    __syncthreads(); }

  #pragma unroll 1
  for (int tt=0; tt<16; tt++){
    BODY(2*tt,   0, Aa, Ab);
    BODY(2*tt+1, 1, Ab, Aa);
  }
  #undef BODY
  #undef STAGE
  #undef LOADA

  // cross-khalf reduction through the (now dead) staging LDS
  float* red = SMEMf;   // [4][64][33]
  if (khalf==1){
    #pragma unroll
    for (int j=0;j<2;j++)
      #pragma unroll
      for (int r=0;r<16;r++)
        red[((qsub*64 + lane)*33) + 16*j + r] = xacc[j][r];
  }
  __syncthreads();
  if (khalf==0){
    #pragma unroll
    for (int j=0;j<2;j++)
      #pragma unroll
      for (int r=0;r<16;r++)
        xacc[j][r] += red[((qsub*64 + lane)*33) + 16*j + r];
    const int b = bh>>4, h = bh&15;
    #pragma unroll
    for (int fj=0; fj<2; fj++){
      const int scol = h*4 + fj*2 + (l31>>4);
      const int lpart = ((l31>>3)&1)*32;
      const int epart = l31&7;
      #pragma unroll
      for (int r=0;r<16;r++){
        const int qq = q32*32 + (r&3) + 8*(r>>2) + 4*hi;
        const int row = b*SEQ + qq;
        const size_t addr = ((size_t)(row>>5)*64 + scol)*512 + (lpart + (row&31))*8 + epart;
        xp[addr] = f2b(xacc[fj][r]);
      }
    }
  }
}

// ---------- output projection: LDS-free fragment GEMM, fp32 out ----------
__global__ __launch_bounds__(256,4) void oproj(
    const unsigned short* __restrict__ Xp, const unsigned short* __restrict__ Wop,
    const float* __restrict__ bo, float* __restrict__ out)
{
  const int orig = blockIdx.y*16 + blockIdx.x;
  const int virt = (orig&7)*64 + (orig>>3);
  const int bx = virt&15, by = virt>>4;
  const int mb = by*128, nb = bx*64;

  const int tid = threadIdx.x;
  const int lane = tid&63, wave = tid>>6;
  const int l31 = lane&31, hi = lane>>5;
  f32x16 acc[2] = {};

  const unsigned short* ap  = Xp  + (size_t)((mb>>5) + wave)*32768 + lane*8;
  const unsigned short* b0p = Wop + (size_t)(nb>>5)*32768 + lane*8;
  const unsigned short* b1p = b0p + 32768;

  #pragma unroll 4
  for (int s=0;s<64;s++){
    bf16x8 a  = *(const bf16x8*)(ap  + (size_t)s*512);
    bf16x8 b0 = *(const bf16x8*)(b0p + (size_t)s*512);
    bf16x8 b1 = *(const bf16x8*)(b1p + (size_t)s*512);
    acc[0] = mfma32(a,b0,acc[0]);
    acc[1] = mfma32(a,b1,acc[1]);
  }

  #pragma unroll
  for (int fj=0; fj<2; fj++){
    const int e = nb + 32*fj + l31;
    const float bv_ = bo[e];
    #pragma unroll
    for (int r=0;r<16;r++){
      const int i = mb + 32*wave + (r&3) + 8*(r>>2) + 4*hi;
      out[(size_t)i*DMODEL + e] = acc[fj][r] + bv_;
    }
  }
}

extern "C" void kernel_launch(void* const* d_in, const int* in_sizes, int n_in,
                              void* d_out, int out_size, void* d_ws, size_t ws_size,
                              hipStream_t stream)
{
  const float* q  = (const float*)d_in[0];
  const float* k  = (const float*)d_in[1];
  const float* v  = (const float*)d_in[2];
  const float* A  = (const float*)d_in[3];
  const float* Wq = (const float*)d_in[4];
  const float* bq = (const float*)d_in[5];
  const float* Wk = (const float*)d_in[6];
  const float* bk = (const float*)d_in[7];
  const float* Wv = (const float*)d_in[8];
  const float* bv = (const float*)d_in[9];
  const float* Wo = (const float*)d_in[10];
  const float* bo = (const float*)d_in[11];
  float* out = (float*)d_out;

  // ws (bf16 elems): qh, Kp, Vp, xb, Wp -> 40MB. d_out as scratch:
  //   phase1: Xqp [0,8MB), Xkp [8,16MB)   (consumed by proj)
  //   phase2: Am bf16 [0,8MB)             (written by cvtA after proj, read by attn)
  //   phase3: final fp32 out              (oproj)
  unsigned short* ws = (unsigned short*)d_ws;
  const size_t NE = (size_t)NBATCH*SEQ*DMODEL;   // 4M elements
  unsigned short* qh  = ws;
  unsigned short* Kp  = qh + NE;
  unsigned short* Vp  = Kp + NE;
  unsigned short* xb  = Vp + NE;                 // Xvp before attn, packed-x after
  unsigned short* Wp  = xb + NE;                 // 4 packed weight matrices
  unsigned short* Xqp = (unsigned short*)d_out;
  unsigned short* Xkp = Xqp + NE;
  unsigned short* Am  = (unsigned short*)d_out;  // bf16 2048x2048 = 8MB
  unsigned short* Xvp = xb;

  cvtXpack<<<dim3(128, 1, 3), 256, 0, stream>>>(q, k, v, Xqp, Xkp, Xvp);
  cvtWpack<<<dim3(32, 1, 4), 256, 0, stream>>>(Wq, Wk, Wv, Wo, Wp);
  proj_qkv<<<dim3(8, 32, 3), 256, 0, stream>>>(
      Xqp, Xkp, Xvp, Wp, bq, bk, bv, qh, Kp, Vp);
  cvtA<<<dim3(64, 8), 256, 0, stream>>>(A, Am);
  attn<<<dim3(16, 32), 512, 0, stream>>>(qh, Kp, Vp, Am, xb);
  oproj<<<dim3(16, 32), 256, 0, stream>>>(xb, Wp + (size_t)3*1048576, bo, out);
}

// Round 13
// 130.748 us; speedup vs baseline: 2.4365x; 1.0210x over previous
//
#include <hip/hip_runtime.h>

#define SEQ    2048
#define DMODEL 1024
#define NHEAD  16
#define DHEAD  64
#define NBATCH 2

typedef __bf16 bf16x8 __attribute__((ext_vector_type(8)));
typedef float f32x16 __attribute__((ext_vector_type(16)));
typedef float f32x8 __attribute__((ext_vector_type(8)));
typedef unsigned short ushort8v __attribute__((ext_vector_type(8)));
typedef unsigned int uint2v __attribute__((ext_vector_type(2)));
typedef int int4v __attribute__((ext_vector_type(4)));

static __device__ __forceinline__ unsigned short f2b(float f){
  unsigned int u = __builtin_bit_cast(unsigned int, f);
  u += 0x7fffu + ((u>>16)&1u);            // RNE to bf16
  return (unsigned short)(u>>16);
}
static __device__ __forceinline__ float b2f(unsigned short h){
  unsigned int u = ((unsigned int)h)<<16;
  return __builtin_bit_cast(float, u);
}
static __device__ __forceinline__ f32x16 mfma32(bf16x8 a, bf16x8 b, f32x16 c){
  return __builtin_amdgcn_mfma_f32_32x32x16_bf16(a,b,c,0,0,0);
}
static __device__ __forceinline__ ushort8v cvt8(const float* p){
  float4 f0 = *(const float4*)p;
  float4 f1 = *(const float4*)(p+4);
  ushort8v r;
  r[0]=f2b(f0.x); r[1]=f2b(f0.y); r[2]=f2b(f0.z); r[3]=f2b(f0.w);
  r[4]=f2b(f1.x); r[5]=f2b(f1.y); r[6]=f2b(f1.z); r[7]=f2b(f1.w);
  return r;
}
#define GLOAD16(g,l) __builtin_amdgcn_global_load_lds( \
    (const __attribute__((address_space(1))) void*)(g), \
    (__attribute__((address_space(3))) void*)(l), 16, 0, 0)

// ---------- pack X (q,k,v) and W (q,k,v,o) fp32 -> bf16 MFMA fragment order ----------
// z=0..2: Xp[g][s][lane][8] = X[g*32 + (lane&31)][16*s + 8*(lane>>5) + j], g=0..127
// z=3   : Wp[wz*32+g][s][lane][8] for the 4 weight matrices, blockIdx.x = wz*32+g
__global__ __launch_bounds__(256) void cvtXW(
    const float* __restrict__ q, const float* __restrict__ k, const float* __restrict__ v,
    const float* __restrict__ Wq, const float* __restrict__ Wk,
    const float* __restrict__ Wv, const float* __restrict__ Wo,
    unsigned short* __restrict__ Xq, unsigned short* __restrict__ Xk, unsigned short* __restrict__ Xv,
    unsigned short* __restrict__ Wp)
{
  const int z = blockIdx.z;
  const int wave = threadIdx.x>>6, lane = threadIdx.x&63;
  const int l31 = lane&31, hi = lane>>5;
  const float* S;
  unsigned short* dst;
  int g;
  if (z < 3){
    S = (z==0)? q : (z==1)? k : v;
    unsigned short* D = (z==0)? Xq : (z==1)? Xk : Xv;
    g = blockIdx.x;                       // 0..127
    dst = D + (size_t)(g*64 + wave*16)*512 + lane*8;
  } else {
    const int wz = blockIdx.x>>5, gg = blockIdx.x&31;
    S = (wz==0)? Wq : (wz==1)? Wk : (wz==2)? Wv : Wo;
    g = gg;
    dst = Wp + (size_t)((wz*32 + gg)*64 + wave*16)*512 + lane*8;
  }
  const float* src = S + (size_t)(g*32 + l31)*DMODEL + 8*hi + 256*wave;
  #pragma unroll
  for (int i=0;i<16;i++)
    *(ushort8v*)(dst + (size_t)i*512) = cvt8(src + 16*i);
}

// ---------- A packer (bf16): Am[q32][kt][w][lane][8] = bf16(A[k][q]) ----------
__global__ __launch_bounds__(256) void cvtA(const float* __restrict__ A,
                                            unsigned short* __restrict__ Am){
  const int tid  = threadIdx.x;
  const int lane = tid&63, l31 = lane&31, hi = lane>>5;
  const int q32  = blockIdx.x;                 // 0..63
  const int kt   = blockIdx.y*4 + (tid>>6);    // 0..31
  const int q    = q32*32 + l31;

  unsigned short out8[4][8];
  #pragma unroll
  for (int fi=0; fi<2; fi++){
    #pragma unroll
    for (int mm=0; mm<4; mm++){
      #pragma unroll
      for (int j=0; j<4; j++){
        const int k = kt*64 + 32*fi + 8*mm + 4*hi + j;
        out8[fi*2 + (mm>>1)][(mm&1)*4 + j] = f2b(A[(size_t)k*SEQ + q]);
      }
    }
  }
  unsigned short* dst = Am + ((size_t)(q32*32 + kt)*4)*512 + lane*8;
  #pragma unroll
  for (int w=0; w<4; w++)
    *(ushort8v*)(dst + (size_t)w*512) = *(const ushort8v*)out8[w];
}

// ---------- fused q/k/v projection: LDS-free, barrier-free fragment GEMM ----------
__global__ __launch_bounds__(256,3) void proj_qkv(
    const unsigned short* __restrict__ Xq, const unsigned short* __restrict__ Xk, const unsigned short* __restrict__ Xv,
    const unsigned short* __restrict__ Wp,
    const float* __restrict__ bq, const float* __restrict__ bk, const float* __restrict__ bv,
    unsigned short* __restrict__ qh, unsigned short* __restrict__ Kp, unsigned short* __restrict__ Vp)
{
  const int z = blockIdx.z;
  const unsigned short* X = (z==0)? Xq : (z==1)? Xk : Xv;
  const unsigned short* W = Wp + (size_t)z*1048576;
  const float* bias = (z==0)? bq : (z==1)? bk : bv;
  const float alpha = (z==0)? 0.125f : 1.0f;   // fold 1/sqrt(DK) into qh

  const int orig = blockIdx.y*8 + blockIdx.x;
  const int virt = (orig&7)*32 + (orig>>3);
  const int bx = virt&7, by = virt>>3;
  const int mb = by*128, nb = bx*128;

  const int tid = threadIdx.x;
  const int lane = tid&63, wave = tid>>6;
  const int wr = wave>>1, wc = wave&1, l31 = lane&31, hi = lane>>5;
  f32x16 acc[2][2] = {};

  const unsigned short* a0p = X + (size_t)((mb>>5) + 2*wr)*32768 + lane*8;
  const unsigned short* a1p = a0p + 32768;
  const unsigned short* b0p = W + (size_t)((nb>>5) + 2*wc)*32768 + lane*8;
  const unsigned short* b1p = b0p + 32768;

  #pragma unroll 4
  for (int s=0;s<64;s++){
    bf16x8 a0 = *(const bf16x8*)(a0p + (size_t)s*512);
    bf16x8 a1 = *(const bf16x8*)(a1p + (size_t)s*512);
    bf16x8 b0 = *(const bf16x8*)(b0p + (size_t)s*512);
    bf16x8 b1 = *(const bf16x8*)(b1p + (size_t)s*512);
    acc[0][0] = mfma32(a0,b0,acc[0][0]);
    acc[0][1] = mfma32(a0,b1,acc[0][1]);
    acc[1][0] = mfma32(a1,b0,acc[1][0]);
    acc[1][1] = mfma32(a1,b1,acc[1][1]);
  }

  #pragma unroll
  for (int fj=0; fj<2; fj++){
    const int e = nb + 64*wc + 32*fj + l31;
    const float bv_ = bias[e];
    const int hh = e>>6, dk = e&63;
    #pragma unroll
    for (int fi=0; fi<2; fi++){
      #pragma unroll
      for (int r=0;r<16;r++){
        const int i = mb + 64*wr + 32*fi + (r&3) + 8*(r>>2) + 4*hi;
        const int bb = i>>11, ss = i&(SEQ-1);
        const int bhh = bb*NHEAD + hh;
        const unsigned short val = f2b((acc[fi][fj][r] + bv_)*alpha);
        if (z==0){
          qh[((size_t)bhh*SEQ + ss)*DHEAD + dk] = val;
        } else if (z==1){
          const size_t addr = (((size_t)(bhh*64 + (ss>>5))*4 + (dk>>4))*64
                               + ((dk>>3)&1)*32 + (ss&31))*8 + (dk&7);
          Kp[addr] = val;
        } else {
          const size_t addr = ((((size_t)(bhh*32 + (ss>>6))*4 + ((ss>>4)&3))*2
                               + (dk>>5))*64 + ((ss>>3)&1)*32 + (dk&31))*8 + (ss&7);
          Vp[addr] = val;
        }
      }
    }
  }
}

// ---------- fused masked attention: x = (Qh Kh^T ∘ A^T) Vh ----------
// 512 threads = 8 waves = 4 qsub x 2 khalf; 128 q-rows/block; 512 blocks = 2/CU.
// K/V staged in PAIRS of k-tiles (KBLK=128) -> compute per barrier (~2x) now
// covers the gload_lds L2 latency; 16 barriers instead of 32.
__global__ __launch_bounds__(512,4) void attn(
    const unsigned short* __restrict__ qh, const unsigned short* __restrict__ Kp,
    const unsigned short* __restrict__ Vp, const unsigned short* __restrict__ Am,
    unsigned short* __restrict__ xp)
{
  // 512 blocks: xcd = orig&7 owns bh in [xcd*4, xcd*4+4) -> K/V slice L2-resident
  const int orig = blockIdx.y*16 + blockIdx.x;
  const int xcd = orig&7, within = orig>>3;   // within 0..63
  const int bh   = xcd*4 + (within>>4);       // 0..31
  const int qblk = within&15;                 // 0..15 (128 q-rows each)

  const int tid  = threadIdx.x;
  const int lane = tid&63, wave = tid>>6;     // wave 0..7
  const int qsub = wave&3, khalf = wave>>2;
  const int l31 = lane&31, hi = lane>>5;

  const int q32  = qblk*4 + qsub;
  const int qrow = q32*32 + l31;
  const unsigned short* qp = qh + ((size_t)bh*SEQ + qrow)*DHEAD;
  bf16x8 Qf[4];
  #pragma unroll
  for (int t=0;t<4;t++) Qf[t] = *(const bf16x8*)(qp + 16*t + 8*hi);

  f32x16 xacc[2] = {};

  const unsigned short* kpb = Kp + (size_t)bh*131072 + lane*8;   // [kt][frag][lane][8]
  const unsigned short* vpb = Vp + (size_t)bh*131072 + lane*8;
  const unsigned short* apb = Am + (size_t)q32*65536 + lane*8;   // [kt][w][lane][8]

  // staging: [buf][tile-in-pair][16 frags (K 0..7 | V 8..15)][512 shorts] = 64 KB;
  // reused post-loop as float red[4][64][33] (33792 B)
  __shared__ float SMEMf[16384];
  unsigned short* smem = (unsigned short*)SMEMf;

  // wave w stages combined frags {2w, 2w+1} of each tile
  const unsigned short* gsb = ((wave<4)? kpb : vpb);
  const int fo = (wave&3)*2;                       // fragment pair within K or V
  const int dof = ((wave<4)? 0 : 4096) + fo*512;   // LDS dest offset (shorts)

  ushort8v Aa[2][2], Ab[2][2];   // [tile-in-pair][half]

  // stage pair PT (tiles 2PT, 2PT+1) into buffer BUF
  #define STAGE2(BUF, PT) { \
    _Pragma("unroll") \
    for (int tp=0; tp<2; tp++){ \
      const unsigned short* _g = gsb + (size_t)((PT)*2+tp)*4096 + (size_t)fo*512; \
      GLOAD16(_g,       smem + (BUF)*16384 + tp*8192 + dof); \
      GLOAD16(_g + 512, smem + (BUF)*16384 + tp*8192 + dof + 512); } }

  #define LOADA2(DST, PT) { \
    _Pragma("unroll") \
    for (int tp=0; tp<2; tp++){ \
      const unsigned short* _ap = apb + (size_t)((PT)*2+tp)*2048 + (size_t)(khalf*2)*512; \
      DST[tp][0] = *(const ushort8v*)(_ap); \
      DST[tp][1] = *(const ushort8v*)(_ap + 512); } }

  STAGE2(0, 0);
  LOADA2(Aa, 0);
  __syncthreads();

  // compute one tile (TP-th of the pair in buffer BUF) with mask regs AR
  #define TILE(BUF, TP, AR) { \
    unsigned int wv[4], xv[4]; \
    { \
      f32x16 sacc = {}; \
      _Pragma("unroll") \
      for (int s=0;s<4;s++){ \
        bf16x8 kf = *(const bf16x8*)(smem + (BUF)*16384 + (TP)*8192 + (khalf*4+s)*512 + lane*8); \
        sacc = mfma32(kf, Qf[s], sacc); \
      } \
      ushort8v a80 = AR[0], a81 = AR[1]; \
      _Pragma("unroll") \
      for (int mm=0; mm<4; mm++){ \
        const int b0 = (mm&1)*4, rb2 = 4*mm; \
        float p0 = sacc[rb2+0]*((mm>>1)? b2f(a81[b0+0]) : b2f(a80[b0+0])); \
        float p1 = sacc[rb2+1]*((mm>>1)? b2f(a81[b0+1]) : b2f(a80[b0+1])); \
        float p2 = sacc[rb2+2]*((mm>>1)? b2f(a81[b0+2]) : b2f(a80[b0+2])); \
        float p3 = sacc[rb2+3]*((mm>>1)? b2f(a81[b0+3]) : b2f(a80[b0+3])); \
        asm("v_cvt_pk_bf16_f32 %0, %1, %2" : "=v"(wv[mm]) : "v"(p0), "v"(p1)); \
        asm("v_cvt_pk_bf16_f32 %0, %1, %2" : "=v"(xv[mm]) : "v"(p2), "v"(p3)); \
      } \
    } \
    __builtin_amdgcn_s_setprio(1); \
    _Pragma("unroll") \
    for (int sl=0; sl<2; sl++){ \
      const int s2 = 2*khalf + sl; \
      uint2v rw = __builtin_amdgcn_permlane32_swap(wv[2*sl], wv[2*sl+1], false, false); \
      uint2v rx = __builtin_amdgcn_permlane32_swap(xv[2*sl], xv[2*sl+1], false, false); \
      int4v av; av.x = (int)rw[0]; av.y = (int)rx[0]; av.z = (int)rw[1]; av.w = (int)rx[1]; \
      bf16x8 pa = __builtin_bit_cast(bf16x8, av); \
      bf16x8 v0 = *(const bf16x8*)(smem + (BUF)*16384 + (TP)*8192 + 4096 + (s2*2+0)*512 + lane*8); \
      bf16x8 v1 = *(const bf16x8*)(smem + (BUF)*16384 + (TP)*8192 + 4096 + (s2*2+1)*512 + lane*8); \
      xacc[0] = mfma32(pa, v0, xacc[0]); \
      xacc[1] = mfma32(pa, v1, xacc[1]); \
    } \
    __builtin_amdgcn_s_setprio(0); }

  // BODYP: stage next pair into BUF^1, prefetch its A; compute both tiles of BUF
  #define BODYP(BUF, PT, AR, AN) { \
    STAGE2((BUF)^1, ((PT)+1)&15); \
    LOADA2(AN, ((PT)+1)&15); \
    TILE(BUF, 0, AR[0]); \
    TILE(BUF, 1, AR[1]); \
    __syncthreads(); }

  #pragma unroll 1
  for (int uu=0; uu<8; uu++){
    BODYP(0, 2*uu,   Aa, Ab);
    BODYP(1, 2*uu+1, Ab, Aa);
  }
  #undef BODYP
  #undef TILE
  #undef STAGE2
  #undef LOADA2

  // cross-khalf reduction through the (now dead) staging LDS
  float* red = SMEMf;   // [4][64][33]
  if (khalf==1){
    #pragma unroll
    for (int j=0;j<2;j++)
      #pragma unroll
      for (int r=0;r<16;r++)
        red[((qsub*64 + lane)*33) + 16*j + r] = xacc[j][r];
  }
  __syncthreads();
  if (khalf==0){
    #pragma unroll
    for (int j=0;j<2;j++)
      #pragma unroll
      for (int r=0;r<16;r++)
        xacc[j][r] += red[((qsub*64 + lane)*33) + 16*j + r];
    const int b = bh>>4, h = bh&15;
    #pragma unroll
    for (int fj=0; fj<2; fj++){
      const int scol = h*4 + fj*2 + (l31>>4);
      const int lpart = ((l31>>3)&1)*32;
      const int epart = l31&7;
      #pragma unroll
      for (int r=0;r<16;r++){
        const int qq = q32*32 + (r&3) + 8*(r>>2) + 4*hi;
        const int row = b*SEQ + qq;
        const size_t addr = ((size_t)(row>>5)*64 + scol)*512 + (lpart + (row&31))*8 + epart;
        xp[addr] = f2b(xacc[fj][r]);
      }
    }
  }
}

// ---------- output projection: LDS-free fragment GEMM, fp32 out ----------
__global__ __launch_bounds__(256,4) void oproj(
    const unsigned short* __restrict__ Xp, const unsigned short* __restrict__ Wop,
    const float* __restrict__ bo, float* __restrict__ out)
{
  const int orig = blockIdx.y*16 + blockIdx.x;
  const int virt = (orig&7)*64 + (orig>>3);
  const int bx = virt&15, by = virt>>4;
  const int mb = by*128, nb = bx*64;

  const int tid = threadIdx.x;
  const int lane = tid&63, wave = tid>>6;
  const int l31 = lane&31, hi = lane>>5;
  f32x16 acc[2] = {};

  const unsigned short* ap  = Xp  + (size_t)((mb>>5) + wave)*32768 + lane*8;
  const unsigned short* b0p = Wop + (size_t)(nb>>5)*32768 + lane*8;
  const unsigned short* b1p = b0p + 32768;

  #pragma unroll 4
  for (int s=0;s<64;s++){
    bf16x8 a  = *(const bf16x8*)(ap  + (size_t)s*512);
    bf16x8 b0 = *(const bf16x8*)(b0p + (size_t)s*512);
    bf16x8 b1 = *(const bf16x8*)(b1p + (size_t)s*512);
    acc[0] = mfma32(a,b0,acc[0]);
    acc[1] = mfma32(a,b1,acc[1]);
  }

  #pragma unroll
  for (int fj=0; fj<2; fj++){
    const int e = nb + 32*fj + l31;
    const float bv_ = bo[e];
    #pragma unroll
    for (int r=0;r<16;r++){
      const int i = mb + 32*wave + (r&3) + 8*(r>>2) + 4*hi;
      out[(size_t)i*DMODEL + e] = acc[fj][r] + bv_;
    }
  }
}

extern "C" void kernel_launch(void* const* d_in, const int* in_sizes, int n_in,
                              void* d_out, int out_size, void* d_ws, size_t ws_size,
                              hipStream_t stream)
{
  const float* q  = (const float*)d_in[0];
  const float* k  = (const float*)d_in[1];
  const float* v  = (const float*)d_in[2];
  const float* A  = (const float*)d_in[3];
  const float* Wq = (const float*)d_in[4];
  const float* bq = (const float*)d_in[5];
  const float* Wk = (const float*)d_in[6];
  const float* bk = (const float*)d_in[7];
  const float* Wv = (const float*)d_in[8];
  const float* bv = (const float*)d_in[9];
  const float* Wo = (const float*)d_in[10];
  const float* bo = (const float*)d_in[11];
  float* out = (float*)d_out;

  // ws (bf16 elems): qh, Kp, Vp, xb, Wp -> 40MB. d_out as scratch:
  //   phase1: Xqp [0,8MB), Xkp [8,16MB)   (consumed by proj)
  //   phase2: Am bf16 [0,8MB)             (written by cvtA after proj, read by attn)
  //   phase3: final fp32 out              (oproj)
  unsigned short* ws = (unsigned short*)d_ws;
  const size_t NE = (size_t)NBATCH*SEQ*DMODEL;   // 4M elements
  unsigned short* qh  = ws;
  unsigned short* Kp  = qh + NE;
  unsigned short* Vp  = Kp + NE;
  unsigned short* xb  = Vp + NE;                 // Xvp before attn, packed-x after
  unsigned short* Wp  = xb + NE;                 // 4 packed weight matrices
  unsigned short* Xqp = (unsigned short*)d_out;
  unsigned short* Xkp = Xqp + NE;
  unsigned short* Am  = (unsigned short*)d_out;  // bf16 2048x2048 = 8MB
  unsigned short* Xvp = xb;

  cvtXW<<<dim3(128, 1, 4), 256, 0, stream>>>(q, k, v, Wq, Wk, Wv, Wo,
                                             Xqp, Xkp, Xvp, Wp);
  proj_qkv<<<dim3(8, 32, 3), 256, 0, stream>>>(
      Xqp, Xkp, Xvp, Wp, bq, bk, bv, qh, Kp, Vp);
  cvtA<<<dim3(64, 8), 256, 0, stream>>>(A, Am);
  attn<<<dim3(16, 32), 512, 0, stream>>>(qh, Kp, Vp, Am, xb);
  oproj<<<dim3(16, 32), 256, 0, stream>>>(xb, Wp + (size_t)3*1048576, bo, out);
}

// Round 14
// 129.901 us; speedup vs baseline: 2.4524x; 1.0065x over previous
//
#include <hip/hip_runtime.h>

#define SEQ    2048
#define DMODEL 1024
#define NHEAD  16
#define DHEAD  64
#define NBATCH 2

typedef __bf16 bf16x8 __attribute__((ext_vector_type(8)));
typedef float f32x16 __attribute__((ext_vector_type(16)));
typedef float f32x8 __attribute__((ext_vector_type(8)));
typedef unsigned short ushort8v __attribute__((ext_vector_type(8)));
typedef unsigned int uint2v __attribute__((ext_vector_type(2)));
typedef int int4v __attribute__((ext_vector_type(4)));

static __device__ __forceinline__ unsigned short f2b(float f){
  unsigned int u = __builtin_bit_cast(unsigned int, f);
  u += 0x7fffu + ((u>>16)&1u);            // RNE to bf16
  return (unsigned short)(u>>16);
}
static __device__ __forceinline__ float b2f(unsigned short h){
  unsigned int u = ((unsigned int)h)<<16;
  return __builtin_bit_cast(float, u);
}
static __device__ __forceinline__ f32x16 mfma32(bf16x8 a, bf16x8 b, f32x16 c){
  return __builtin_amdgcn_mfma_f32_32x32x16_bf16(a,b,c,0,0,0);
}
static __device__ __forceinline__ ushort8v cvt8(const float* p){
  float4 f0 = *(const float4*)p;
  float4 f1 = *(const float4*)(p+4);
  ushort8v r;
  r[0]=f2b(f0.x); r[1]=f2b(f0.y); r[2]=f2b(f0.z); r[3]=f2b(f0.w);
  r[4]=f2b(f1.x); r[5]=f2b(f1.y); r[6]=f2b(f1.z); r[7]=f2b(f1.w);
  return r;
}
#define GLOAD16(g,l) __builtin_amdgcn_global_load_lds( \
    (const __attribute__((address_space(1))) void*)(g), \
    (__attribute__((address_space(3))) void*)(l), 16, 0, 0)

// ---------- pack X (q,k,v) and W (q,k,v,o) fp32 -> bf16 MFMA fragment order ----------
__global__ __launch_bounds__(256) void cvtXW(
    const float* __restrict__ q, const float* __restrict__ k, const float* __restrict__ v,
    const float* __restrict__ Wq, const float* __restrict__ Wk,
    const float* __restrict__ Wv, const float* __restrict__ Wo,
    unsigned short* __restrict__ Xq, unsigned short* __restrict__ Xk, unsigned short* __restrict__ Xv,
    unsigned short* __restrict__ Wp)
{
  const int z = blockIdx.z;
  const int wave = threadIdx.x>>6, lane = threadIdx.x&63;
  const int l31 = lane&31, hi = lane>>5;
  const float* S;
  unsigned short* dst;
  int g;
  if (z < 3){
    S = (z==0)? q : (z==1)? k : v;
    unsigned short* D = (z==0)? Xq : (z==1)? Xk : Xv;
    g = blockIdx.x;                       // 0..127
    dst = D + (size_t)(g*64 + wave*16)*512 + lane*8;
  } else {
    const int wz = blockIdx.x>>5, gg = blockIdx.x&31;
    S = (wz==0)? Wq : (wz==1)? Wk : (wz==2)? Wv : Wo;
    g = gg;
    dst = Wp + (size_t)((wz*32 + gg)*64 + wave*16)*512 + lane*8;
  }
  const float* src = S + (size_t)(g*32 + l31)*DMODEL + 8*hi + 256*wave;
  #pragma unroll
  for (int i=0;i<16;i++)
    *(ushort8v*)(dst + (size_t)i*512) = cvt8(src + 16*i);
}

// ---------- A packer (bf16): Am[q32][kt][w][lane][8] = bf16(A[k][q]) ----------
__global__ __launch_bounds__(256) void cvtA(const float* __restrict__ A,
                                            unsigned short* __restrict__ Am){
  const int tid  = threadIdx.x;
  const int lane = tid&63, l31 = lane&31, hi = lane>>5;
  const int q32  = blockIdx.x;                 // 0..63
  const int kt   = blockIdx.y*4 + (tid>>6);    // 0..31
  const int q    = q32*32 + l31;

  unsigned short out8[4][8];
  #pragma unroll
  for (int fi=0; fi<2; fi++){
    #pragma unroll
    for (int mm=0; mm<4; mm++){
      #pragma unroll
      for (int j=0; j<4; j++){
        const int k = kt*64 + 32*fi + 8*mm + 4*hi + j;
        out8[fi*2 + (mm>>1)][(mm&1)*4 + j] = f2b(A[(size_t)k*SEQ + q]);
      }
    }
  }
  unsigned short* dst = Am + ((size_t)(q32*32 + kt)*4)*512 + lane*8;
  #pragma unroll
  for (int w=0; w<4; w++)
    *(ushort8v*)(dst + (size_t)w*512) = *(const ushort8v*)out8[w];
}

// ---------- fused q/k/v projection: LDS-free, barrier-free fragment GEMM ----------
__global__ __launch_bounds__(256,3) void proj_qkv(
    const unsigned short* __restrict__ Xq, const unsigned short* __restrict__ Xk, const unsigned short* __restrict__ Xv,
    const unsigned short* __restrict__ Wp,
    const float* __restrict__ bq, const float* __restrict__ bk, const float* __restrict__ bv,
    unsigned short* __restrict__ qh, unsigned short* __restrict__ Kp, unsigned short* __restrict__ Vp)
{
  const int z = blockIdx.z;
  const unsigned short* X = (z==0)? Xq : (z==1)? Xk : Xv;
  const unsigned short* W = Wp + (size_t)z*1048576;
  const float* bias = (z==0)? bq : (z==1)? bk : bv;
  const float alpha = (z==0)? 0.125f : 1.0f;   // fold 1/sqrt(DK) into qh

  const int orig = blockIdx.y*8 + blockIdx.x;
  const int virt = (orig&7)*32 + (orig>>3);
  const int bx = virt&7, by = virt>>3;
  const int mb = by*128, nb = bx*128;

  const int tid = threadIdx.x;
  const int lane = tid&63, wave = tid>>6;
  const int wr = wave>>1, wc = wave&1, l31 = lane&31, hi = lane>>5;
  f32x16 acc[2][2] = {};

  const unsigned short* a0p = X + (size_t)((mb>>5) + 2*wr)*32768 + lane*8;
  const unsigned short* a1p = a0p + 32768;
  const unsigned short* b0p = W + (size_t)((nb>>5) + 2*wc)*32768 + lane*8;
  const unsigned short* b1p = b0p + 32768;

  #pragma unroll 4
  for (int s=0;s<64;s++){
    bf16x8 a0 = *(const bf16x8*)(a0p + (size_t)s*512);
    bf16x8 a1 = *(const bf16x8*)(a1p + (size_t)s*512);
    bf16x8 b0 = *(const bf16x8*)(b0p + (size_t)s*512);
    bf16x8 b1 = *(const bf16x8*)(b1p + (size_t)s*512);
    acc[0][0] = mfma32(a0,b0,acc[0][0]);
    acc[0][1] = mfma32(a0,b1,acc[0][1]);
    acc[1][0] = mfma32(a1,b0,acc[1][0]);
    acc[1][1] = mfma32(a1,b1,acc[1][1]);
  }

  #pragma unroll
  for (int fj=0; fj<2; fj++){
    const int e = nb + 64*wc + 32*fj + l31;
    const float bv_ = bias[e];
    const int hh = e>>6, dk = e&63;
    #pragma unroll
    for (int fi=0; fi<2; fi++){
      #pragma unroll
      for (int r=0;r<16;r++){
        const int i = mb + 64*wr + 32*fi + (r&3) + 8*(r>>2) + 4*hi;
        const int bb = i>>11, ss = i&(SEQ-1);
        const int bhh = bb*NHEAD + hh;
        const unsigned short val = f2b((acc[fi][fj][r] + bv_)*alpha);
        if (z==0){
          qh[((size_t)bhh*SEQ + ss)*DHEAD + dk] = val;
        } else if (z==1){
          const size_t addr = (((size_t)(bhh*64 + (ss>>5))*4 + (dk>>4))*64
                               + ((dk>>3)&1)*32 + (ss&31))*8 + (dk&7);
          Kp[addr] = val;
        } else {
          const size_t addr = ((((size_t)(bhh*32 + (ss>>6))*4 + ((ss>>4)&3))*2
                               + (dk>>5))*64 + ((ss>>3)&1)*32 + (dk&31))*8 + (ss&7);
          Vp[addr] = val;
        }
      }
    }
  }
}

// ---------- fused masked attention: x = (Qh Kh^T ∘ A^T) Vh ----------
// R12 structure (measured 44.8us): 512 thr = 4 qsub x 2 khalf; KBLK=64 dbuf;
// shared K/V LDS stream via global_load_lds; fi-split per khalf.
__global__ __launch_bounds__(512,4) void attn(
    const unsigned short* __restrict__ qh, const unsigned short* __restrict__ Kp,
    const unsigned short* __restrict__ Vp, const unsigned short* __restrict__ Am,
    unsigned short* __restrict__ xp)
{
  const int orig = blockIdx.y*16 + blockIdx.x;
  const int xcd = orig&7, within = orig>>3;   // within 0..63
  const int bh   = xcd*4 + (within>>4);       // 0..31
  const int qblk = within&15;                 // 0..15 (128 q-rows each)

  const int tid  = threadIdx.x;
  const int lane = tid&63, wave = tid>>6;     // wave 0..7
  const int qsub = wave&3, khalf = wave>>2;
  const int l31 = lane&31, hi = lane>>5;

  const int q32  = qblk*4 + qsub;
  const int qrow = q32*32 + l31;
  const unsigned short* qp = qh + ((size_t)bh*SEQ + qrow)*DHEAD;
  bf16x8 Qf[4];
  #pragma unroll
  for (int t=0;t<4;t++) Qf[t] = *(const bf16x8*)(qp + 16*t + 8*hi);

  f32x16 xacc[2] = {};

  const unsigned short* kpb = Kp + (size_t)bh*131072 + lane*8;   // [kt][frag][lane][8]
  const unsigned short* vpb = Vp + (size_t)bh*131072 + lane*8;
  const unsigned short* apb = Am + (size_t)q32*65536 + lane*8;   // [kt][w][lane][8]

  // staging: [buf][16 frags (K 0..7 | V 8..15)][512 shorts] = 32 KB;
  // reused post-loop as float Red[4][64][33] = 33792 B
  __shared__ float SMEMf[8448];
  unsigned short* smem = (unsigned short*)SMEMf;

  const unsigned short* gsb = ((wave<4)? kpb : vpb);
  const int fo = (wave&3)*2;                       // fragment pair within K or V
  const int dof = ((wave<4)? 0 : 4096) + fo*512;   // LDS dest offset (shorts)

  ushort8v Aa[2], Ab[2];

  #define STAGE(BUF, KT) { \
    const unsigned short* _g = gsb + (size_t)(KT)*4096 + (size_t)fo*512; \
    GLOAD16(_g,       smem + (BUF)*8192 + dof); \
    GLOAD16(_g + 512, smem + (BUF)*8192 + dof + 512); }

  #define LOADA(DST, KT) { \
    const unsigned short* _ap = apb + (size_t)(KT)*2048 + (size_t)(khalf*2)*512; \
    DST[0] = *(const ushort8v*)(_ap); \
    DST[1] = *(const ushort8v*)(_ap + 512); }

  STAGE(0, 0);
  LOADA(Aa, 0);
  __syncthreads();

  #define BODY(KT, BUF, AR, AN) { \
    STAGE((BUF)^1, ((KT)+1)&31); \
    LOADA(AN, ((KT)+1)&31); \
    unsigned int wv[4], xv[4]; \
    { \
      f32x16 sacc = {}; \
      _Pragma("unroll") \
      for (int s=0;s<4;s++){ \
        bf16x8 kf = *(const bf16x8*)(smem + (BUF)*8192 + (khalf*4+s)*512 + lane*8); \
        sacc = mfma32(kf, Qf[s], sacc); \
      } \
      ushort8v a80 = AR[0], a81 = AR[1]; \
      _Pragma("unroll") \
      for (int mm=0; mm<4; mm++){ \
        const int b0 = (mm&1)*4, rb2 = 4*mm; \
        float p0 = sacc[rb2+0]*((mm>>1)? b2f(a81[b0+0]) : b2f(a80[b0+0])); \
        float p1 = sacc[rb2+1]*((mm>>1)? b2f(a81[b0+1]) : b2f(a80[b0+1])); \
        float p2 = sacc[rb2+2]*((mm>>1)? b2f(a81[b0+2]) : b2f(a80[b0+2])); \
        float p3 = sacc[rb2+3]*((mm>>1)? b2f(a81[b0+3]) : b2f(a80[b0+3])); \
        asm("v_cvt_pk_bf16_f32 %0, %1, %2" : "=v"(wv[mm]) : "v"(p0), "v"(p1)); \
        asm("v_cvt_pk_bf16_f32 %0, %1, %2" : "=v"(xv[mm]) : "v"(p2), "v"(p3)); \
      } \
    } \
    __builtin_amdgcn_s_setprio(1); \
    _Pragma("unroll") \
    for (int sl=0; sl<2; sl++){ \
      const int s2 = 2*khalf + sl; \
      uint2v rw = __builtin_amdgcn_permlane32_swap(wv[2*sl], wv[2*sl+1], false, false); \
      uint2v rx = __builtin_amdgcn_permlane32_swap(xv[2*sl], xv[2*sl+1], false, false); \
      int4v av; av.x = (int)rw[0]; av.y = (int)rx[0]; av.z = (int)rw[1]; av.w = (int)rx[1]; \
      bf16x8 pa = __builtin_bit_cast(bf16x8, av); \
      bf16x8 v0 = *(const bf16x8*)(smem + (BUF)*8192 + 4096 + (s2*2+0)*512 + lane*8); \
      bf16x8 v1 = *(const bf16x8*)(smem + (BUF)*8192 + 4096 + (s2*2+1)*512 + lane*8); \
      xacc[0] = mfma32(pa, v0, xacc[0]); \
      xacc[1] = mfma32(pa, v1, xacc[1]); \
    } \
    __builtin_amdgcn_s_setprio(0); \
    __syncthreads(); }

  #pragma unroll 1
  for (int tt=0; tt<16; tt++){
    BODY(2*tt,   0, Aa, Ab);
    BODY(2*tt+1, 1, Ab, Aa);
  }
  #undef BODY
  #undef STAGE
  #undef LOADA

  // cross-khalf reduction through the (now dead) staging LDS
  float* red = SMEMf;   // [4][64][33]
  if (khalf==1){
    #pragma unroll
    for (int j=0;j<2;j++)
      #pragma unroll
      for (int r=0;r<16;r++)
        red[((qsub*64 + lane)*33) + 16*j + r] = xacc[j][r];
  }
  __syncthreads();
  if (khalf==0){
    #pragma unroll
    for (int j=0;j<2;j++)
      #pragma unroll
      for (int r=0;r<16;r++)
        xacc[j][r] += red[((qsub*64 + lane)*33) + 16*j + r];
    const int b = bh>>4, h = bh&15;
    #pragma unroll
    for (int fj=0; fj<2; fj++){
      const int scol = h*4 + fj*2 + (l31>>4);
      const int lpart = ((l31>>3)&1)*32;
      const int epart = l31&7;
      #pragma unroll
      for (int r=0;r<16;r++){
        const int qq = q32*32 + (r&3) + 8*(r>>2) + 4*hi;
        const int row = b*SEQ + qq;
        const size_t addr = ((size_t)(row>>5)*64 + scol)*512 + (lpart + (row&31))*8 + epart;
        xp[addr] = f2b(xacc[fj][r]);
      }
    }
  }
}

// ---------- output projection: 128x128 fragment GEMM (proj clone), fp32 out ----------
__global__ __launch_bounds__(256,3) void oproj(
    const unsigned short* __restrict__ Xp, const unsigned short* __restrict__ Wop,
    const float* __restrict__ bo, float* __restrict__ out)
{
  const int orig = blockIdx.y*8 + blockIdx.x;
  const int virt = (orig&7)*32 + (orig>>3);
  const int bx = virt&7, by = virt>>3;
  const int mb = by*128, nb = bx*128;

  const int tid = threadIdx.x;
  const int lane = tid&63, wave = tid>>6;
  const int wr = wave>>1, wc = wave&1, l31 = lane&31, hi = lane>>5;
  f32x16 acc[2][2] = {};

  const unsigned short* a0p = Xp  + (size_t)((mb>>5) + 2*wr)*32768 + lane*8;
  const unsigned short* a1p = a0p + 32768;
  const unsigned short* b0p = Wop + (size_t)((nb>>5) + 2*wc)*32768 + lane*8;
  const unsigned short* b1p = b0p + 32768;

  #pragma unroll 4
  for (int s=0;s<64;s++){
    bf16x8 a0 = *(const bf16x8*)(a0p + (size_t)s*512);
    bf16x8 a1 = *(const bf16x8*)(a1p + (size_t)s*512);
    bf16x8 b0 = *(const bf16x8*)(b0p + (size_t)s*512);
    bf16x8 b1 = *(const bf16x8*)(b1p + (size_t)s*512);
    acc[0][0] = mfma32(a0,b0,acc[0][0]);
    acc[0][1] = mfma32(a0,b1,acc[0][1]);
    acc[1][0] = mfma32(a1,b0,acc[1][0]);
    acc[1][1] = mfma32(a1,b1,acc[1][1]);
  }

  #pragma unroll
  for (int fj=0; fj<2; fj++){
    const int e = nb + 64*wc + 32*fj + l31;
    const float bv_ = bo[e];
    #pragma unroll
    for (int fi=0; fi<2; fi++){
      #pragma unroll
      for (int r=0;r<16;r++){
        const int i = mb + 64*wr + 32*fi + (r&3) + 8*(r>>2) + 4*hi;
        out[(size_t)i*DMODEL + e] = acc[fi][fj][r] + bv_;
      }
    }
  }
}

extern "C" void kernel_launch(void* const* d_in, const int* in_sizes, int n_in,
                              void* d_out, int out_size, void* d_ws, size_t ws_size,
                              hipStream_t stream)
{
  const float* q  = (const float*)d_in[0];
  const float* k  = (const float*)d_in[1];
  const float* v  = (const float*)d_in[2];
  const float* A  = (const float*)d_in[3];
  const float* Wq = (const float*)d_in[4];
  const float* bq = (const float*)d_in[5];
  const float* Wk = (const float*)d_in[6];
  const float* bk = (const float*)d_in[7];
  const float* Wv = (const float*)d_in[8];
  const float* bv = (const float*)d_in[9];
  const float* Wo = (const float*)d_in[10];
  const float* bo = (const float*)d_in[11];
  float* out = (float*)d_out;

  // ws (bf16 elems): qh, Kp, Vp, xb, Wp -> 40MB. d_out as scratch:
  //   phase1: Xqp [0,8MB), Xkp [8,16MB)   (consumed by proj)
  //   phase2: Am bf16 [0,8MB)             (written by cvtA after proj, read by attn)
  //   phase3: final fp32 out              (oproj)
  unsigned short* ws = (unsigned short*)d_ws;
  const size_t NE = (size_t)NBATCH*SEQ*DMODEL;   // 4M elements
  unsigned short* qh  = ws;
  unsigned short* Kp  = qh + NE;
  unsigned short* Vp  = Kp + NE;
  unsigned short* xb  = Vp + NE;                 // Xvp before attn, packed-x after
  unsigned short* Wp  = xb + NE;                 // 4 packed weight matrices
  unsigned short* Xqp = (unsigned short*)d_out;
  unsigned short* Xkp = Xqp + NE;
  unsigned short* Am  = (unsigned short*)d_out;  // bf16 2048x2048 = 8MB
  unsigned short* Xvp = xb;

  cvtXW<<<dim3(128, 1, 4), 256, 0, stream>>>(q, k, v, Wq, Wk, Wv, Wo,
                                             Xqp, Xkp, Xvp, Wp);
  proj_qkv<<<dim3(8, 32, 3), 256, 0, stream>>>(
      Xqp, Xkp, Xvp, Wp, bq, bk, bv, qh, Kp, Vp);
  cvtA<<<dim3(64, 8), 256, 0, stream>>>(A, Am);
  attn<<<dim3(16, 32), 512, 0, stream>>>(qh, Kp, Vp, Am, xb);
  oproj<<<dim3(8, 32), 256, 0, stream>>>(xb, Wp + (size_t)3*1048576, bo, out);
}